// Round 1
// baseline (2061.837 us; speedup 1.0000x reference)
//
#include <hip/hip_runtime.h>
#include <hip/hip_bf16.h>
#include <math.h>

#define NT 1024
#define BSZ 128
#define TSTEPS 32
#define DIN 128
#define DHH 128
#define NSLOT 512
#define EPSF 1e-8f

// LDS: [0,131072) mem bf16[512][128] XOR-swizzled; then float scratch F[7160]
static constexpr int F_FLOATS = 7160;
static constexpr size_t LDS_BYTES = 131072 + F_FLOATS * sizeof(float);

__device__ __forceinline__ float bf_lo(unsigned u) {
  union { unsigned u; float f; } c; c.u = u << 16; return c.f;
}
__device__ __forceinline__ float bf_hi(unsigned u) {
  union { unsigned u; float f; } c; c.u = u & 0xffff0000u; return c.f;
}
__device__ __forceinline__ unsigned short f2us(float f) {
  union { unsigned short s; __hip_bfloat16 h; } c; c.h = __float2bfloat16(f); return c.s;
}
__device__ __forceinline__ unsigned pkbf(float a, float b) {
  union { __hip_bfloat162 h2; unsigned u; } c;
  c.h2 = __float22bfloat162_rn(make_float2(a, b));
  return c.u;
}
__device__ __forceinline__ float sigmoid_(float x) { return 1.0f / (1.0f + __expf(-x)); }
__device__ __forceinline__ float softplus_(float x) {
  return fmaxf(x, 0.0f) + log1pf(__expf(-fabsf(x)));
}
__device__ __forceinline__ float tanh_(float x) {
  float e = __expf(-2.0f * fabsf(x));
  float t = (1.0f - e) / (1.0f + e);
  return copysignf(t, x);
}
__device__ __forceinline__ float waveSum(float v) {
#pragma unroll
  for (int m = 32; m >= 1; m >>= 1) v += __shfl_xor(v, m);
  return v;
}

// LDS-only barrier: does NOT drain vmcnt, so prefetched global loads stay in
// flight across phases. All inter-thread traffic in this kernel is LDS (out is
// write-only), so lgkmcnt(0)+s_barrier gives full __syncthreads semantics here.
__device__ __forceinline__ void bar_lds() {
  asm volatile("s_waitcnt lgkmcnt(0)" ::: "memory");
  __builtin_amdgcn_s_barrier();
}

// One block (1024 threads) per batch element; all 32 steps in-block.
// mem in LDS, rows XOR-swizzled: stored uint4 slot u = c ^ ((n>>2)&3).
// Base = r15-lineage 810us kernel. This round (two mechanisms):
//   A. Cross-barrier VMEM pipelining: all in-loop __syncthreads -> bar_lds
//      (lgkm-only), and every weight panel is prefetched into registers a
//      phase early: w1 (Seg1) issued at prev step's Seg9 end; w3/w3h (Seg3)
//      issued at Seg1 end; wtop (Seg7) at SegF top; wbot (Seg11) at Seg8 top.
//   B. DS-pipe relief: broadcast b32 LDS reads vectorized to b128 —
//      Seg1 v-reads 24->6 (sXt/sH/sR re-ordered contiguous as V[384] in
//      x,h,r order), Seg3 sH 32->8 (+halfslot 16->4), Seg7/11 sH/sR 8->2.
__global__ __launch_bounds__(NT, 4)
void ntm_kernel(const float* __restrict__ x,
                const float* __restrict__ Wxh,
                const float* __restrict__ Whh,
                const float* __restrict__ Wrh,
                const float* __restrict__ bh,
                const float* __restrict__ Wout,
                const float* __restrict__ bout,
                const float* __restrict__ Wr,
                const float* __restrict__ br,
                const float* __restrict__ Ww,
                const float* __restrict__ bw,
                float* __restrict__ out)
{
  extern __shared__ char smem[];
  uint4* memv = (uint4*)smem;              // bf16 mem, row n = 16 uint4 (swizzled)
  float* F = (float*)(smem + 131072);

  const int b = blockIdx.x;
  const int tid = threadIdx.x;
  const int g = tid >> 4, l = tid & 15;    // Phase-B mapping
  const int lane = tid & 63, wid = tid >> 6;

  float* U      = F + 0;      // 2560 multi-use: O/H partials (incl. [2096..2191]
                              //      half-slot partials); eR/eW; p2raw
  float* yP     = F + 2560;   // 2048 Y partials (live across step boundary)
  float* sWprev = F + 4608;   // 512
  float* sWr    = F + 5120;   // 512
  float* sP1    = F + 5632;   // 512 p1; aliased early by krP/kwP packed keys
  float* sOr    = F + 6144;   // 144 (134 used)
  float* sOw    = F + 6288;   // 392: [0..127] k_w, [136..263] e (16B-aligned), [264..391] a
  float* sXt    = F + 6680;   // 128  } contiguous V[384] = [x | h | r]
  float* sH     = F + 6808;   // 128  }  (order matters for Seg1 float4 reads)
  float* sR     = F + 6936;   // 128  }  (ds_add target in Seg 9)
  float* sP     = F + 7064;   // 96: [0]kr2 [1]kw2 [2]SR [3]SW [4]P1 [5]P2; [80..91] scalars
  float* V      = sXt;        // V[i]: i<128 x, i<256 h, else r
  uint4* krP    = (uint4*)(sP1 + 0);
  uint4* kwP    = (uint4*)(sP1 + 64);
  float* eR     = U + 0;
  float* eW     = U + 512;

  // ---- persistent per-thread indices (loop-invariant) ----
  const int s1  = tid >> 6;                 // Seg1 row-seg (== wid)
  const int j2s = (tid & 63) * 2;           // Seg1 col pair
  const int i0s = s1 * 24;                  // Seg1 row base
  const int q3  = (tid >= 786) ? 3 : (tid >= 524) ? 2 : (tid >= 262) ? 1 : 0;
  const int P3  = tid - 262 * q3;
  const int i03 = 32 * q3;
  const float2* p3base;
  int stride3;
  if (P3 < 67) { p3base = (const float2*)(Wr + i03 * 134 + 2 * P3); stride3 = 67; }
  else         { p3base = (const float2*)(Ww + i03 * 390 + 2 * (P3 - 67)); stride3 = 195; }
  const int hs   = wid * 3 + lane;          // half-slot id (valid when lane<3)
  const int i0h  = 96 + 16 * (hs & 1);
  const int cph2 = 2 * (171 + (hs >> 1));
  const int pT  = tid - 512;                // Seg7 upper mapping (tid>=512)
  const int j4T = (pT & 31) * 4, slT = pT >> 5;
  const int j4B = (tid & 31) * 4, slB = tid >> 5;  // Seg11 mapping (tid<512)

  // ---- init ----
  {
    const unsigned short mb = f2us(1e-6f);
    const unsigned w32 = ((unsigned)mb << 16) | mb;
    const uint4 fv = make_uint4(w32, w32, w32, w32);
    for (int i = tid; i < NSLOT * DHH / 8; i += NT) memv[i] = fv;
  }
  for (int i = tid; i < NSLOT; i += NT) sWprev[i] = 1.0f / NSLOT;
  if (tid < DHH) { sH[tid] = 0.0f; sR[tid] = 0.0f; }
  if (tid < DIN) sXt[tid] = x[(size_t)b * TSTEPS * DIN + tid];
  __syncthreads();

  // Seg1 weight panel, software-pipelined across steps (reloaded at Seg9 end)
  float2 w1[24];
#define LOAD_W1()                                                          \
  do {                                                                     \
    _Pragma("unroll")                                                      \
    for (int w = 0; w < 24; ++w) {                                         \
      const int i = i0s + w;                                               \
      const float* Wp = (i < 128) ? (Wxh + i * DHH)                        \
                      : (i < 256) ? (Whh + (i - 128) * DHH)                \
                                  : (Wrh + (i - 256) * DHH);               \
      w1[w] = *(const float2*)(Wp + j2s);                                  \
    }                                                                      \
  } while (0)

  LOAD_W1();

  for (int t = 0; t < TSTEPS; ++t) {
    float2 w3[32];    // Seg3 main panel (issued Seg1-end, used Seg3)
    float2 w3h[16];   // Seg3 half-slot panel (lanes 0-2)
    float4 wtop[8];   // Wout rows 0..127   (issued SegF-top, used Seg7)
    float4 wbot[8];   // Wout rows 128..255 (issued Seg8-top, used Seg11)

    // ==== Seg 1: H partials from register weights; issue Seg3 prefetch ====
    {
      float2 acc = make_float2(0.f, 0.f);
#pragma unroll
      for (int k = 0; k < 6; ++k) {
        const float4 vv = *(const float4*)(V + i0s + 4 * k);
        const float vk[4] = { vv.x, vv.y, vv.z, vv.w };
#pragma unroll
        for (int u = 0; u < 4; ++u) {
          acc.x = fmaf(vk[u], w1[4 * k + u].x, acc.x);
          acc.y = fmaf(vk[u], w1[4 * k + u].y, acc.y);
        }
      }
      *(float2*)(U + s1 * 128 + j2s) = acc;
      // prefetch Seg3 panels (w1 is dead now; stays in flight across 2 barriers)
      if (lane < 3) {
#pragma unroll
        for (int w = 0; w < 16; ++w)
          w3h[w] = *(const float2*)(Ww + (i0h + w) * 390 + cph2);
      }
#pragma unroll
      for (int w = 0; w < 32; ++w) w3[w] = p3base[w * stride3];
      bar_lds();
    }
    // ==== Seg 2: h = tanh(sum + bh) ====
    if (tid < DHH) {
      float a2 = bh[tid];
#pragma unroll
      for (int q2 = 0; q2 < 16; ++q2) a2 += U[q2 * 128 + tid];
      sH[tid] = tanh_(a2);
    }
    bar_lds();

    // ==== Seg 3: O partials, pure register-FMA (weights prefetched) ====
    {
      float2 acc = make_float2(0.f, 0.f);
#pragma unroll
      for (int k = 0; k < 8; ++k) {
        const float4 hv = *(const float4*)(sH + i03 + 4 * k);
        const float hk[4] = { hv.x, hv.y, hv.z, hv.w };
#pragma unroll
        for (int u = 0; u < 4; ++u) {
          acc.x = fmaf(hk[u], w3[4 * k + u].x, acc.x);
          acc.y = fmaf(hk[u], w3[4 * k + u].y, acc.y);
        }
      }
      *(float2*)(U + tid * 2) = acc;
      if (lane < 3) {                       // 48 half-slots, 3 per wave
        float2 acch = make_float2(0.f, 0.f);
#pragma unroll
        for (int k = 0; k < 4; ++k) {
          const float4 hv = *(const float4*)(sH + i0h + 4 * k);
          const float hk[4] = { hv.x, hv.y, hv.z, hv.w };
#pragma unroll
          for (int u = 0; u < 4; ++u) {
            acch.x = fmaf(hk[u], w3h[4 * k + u].x, acch.x);
            acch.y = fmaf(hk[u], w3h[4 * k + u].y, acch.y);
          }
        }
        U[2096 + hs * 2]     = acch.x;
        U[2096 + hs * 2 + 1] = acch.y;
      }
      if (tid == 1023) {
        sP[0] = 0.f; sP[1] = 0.f; sP[2] = 0.f; sP[3] = 0.f; sP[4] = 0.f; sP[5] = 0.f;
      }
      bar_lds();
    }

    // ==== Seg F: fused combine+bias / knorm / e,a transforms / key packing /
    //      head scalars / sR zeroing / y-finalize(t-1); issue wtop prefetch ====
    {
      if (tid >= 512) {                     // Seg7's Wout rows, issued early
#pragma unroll
        for (int w = 0; w < 8; ++w)
          wtop[w] = *(const float4*)(Wout + (8 * slT + w) * DIN + j4T);
      }
      if (tid < 134) {                      // o_r col tid
        float v = 0.f;
#pragma unroll
        for (int q = 0; q < 4; ++q) v += U[tid + 524 * q];
        v += br[tid];
        sOr[tid] = v;
        if (tid < 128) {                    // waves 0,1 whole: |k_r|^2
          float s2 = waveSum(v * v);
          if (lane == 0) atomicAdd(&sP[0], s2);
        }
      } else if (tid == 134) {              // read-head scalars from U directly
        float sc[6];
#pragma unroll
        for (int j = 0; j < 6; ++j) {
          float v = 0.f;
#pragma unroll
          for (int q = 0; q < 4; ++q) v += U[(128 + j) + 524 * q];
          sc[j] = v + br[128 + j];
        }
        sP[80] = softplus_(sc[0]);
        sP[81] = sigmoid_(sc[1]);
        float mx = fmaxf(sc[2], fmaxf(sc[3], sc[4]));
        float e0 = __expf(sc[2] - mx), e1 = __expf(sc[3] - mx), e2 = __expf(sc[4] - mx);
        float es = e0 + e1 + e2;
        sP[82] = e0 / es; sP[83] = e1 / es; sP[84] = e2 / es;
        sP[85] = 1.0f + softplus_(sc[5]);
      } else if (tid == 135) {              // write-head scalars (o_w cols 128..133)
        float sc[6];
#pragma unroll
        for (int j = 0; j < 6; ++j) {
          float v = 0.f;
#pragma unroll
          for (int q = 0; q < 4; ++q) v += U[(262 + j) + 524 * q];
          sc[j] = v + bw[128 + j];
        }
        sP[86] = softplus_(sc[0]);
        sP[87] = sigmoid_(sc[1]);
        float mx = fmaxf(sc[2], fmaxf(sc[3], sc[4]));
        float e0 = __expf(sc[2] - mx), e1 = __expf(sc[3] - mx), e2 = __expf(sc[4] - mx);
        float es = e0 + e1 + e2;
        sP[88] = e0 / es; sP[89] = e1 / es; sP[90] = e2 / es;
        sP[91] = 1.0f + softplus_(sc[5]);
      } else if (tid >= 256 && tid < 512) { // e (256..383) / a (384..511)
        const int cc = tid + 12;            // combined col = 134 + cw, cw = tid-122
        float v = U[cc] + U[cc + 524] + U[cc + 1048];
        if (cc < 476) {
          v += U[cc + 1572];
        } else {                            // q=3 partial split into 2 halves
          const int cw = cc - 134;          // 342..389
          const int e = (cw >> 1) - 171;    // 0..23
          const int base = 2096 + 4 * e + (cw & 1);
          v += U[base] + U[base + 2];
        }
        v += bw[tid - 122];
        sOw[tid - 120] = (tid < 384) ? sigmoid_(v) : tanh_(v);
      } else if (tid >= 512 && tid < 640) { // k_w col cw (waves 8,9 whole): |k_w|^2
        const int cw = tid - 512;
        float v = 0.f;
#pragma unroll
        for (int q = 0; q < 4; ++q) v += U[(134 + cw) + 524 * q];
        v += bw[cw];
        sOw[cw] = v;
        float s2 = waveSum(v * v);
        if (lane == 0) atomicAdd(&sP[1], s2);
      } else if (tid >= 640 && tid < 768) {
        sR[tid - 640] = 0.f;                // Seg-9 ds_add target
      } else if (tid >= 768 && tid < 800) { // bf16 key packing from U (redundant combine)
        const int t2 = tid - 768;
        const int c = t2 & 15;
        union { uint4 v; unsigned short h[8]; } pk;
#pragma unroll
        for (int j = 0; j < 8; ++j) {
          const int col = c * 8 + j;        // 0..127
          float v = 0.f;
#pragma unroll
          for (int q = 0; q < 4; ++q)
            v += U[((t2 < 16) ? col : (134 + col)) + 524 * q];
          v += (t2 < 16) ? br[col] : bw[col];
          pk.h[j] = f2us(v);
        }
        if (t2 < 16) krP[c] = pk.v; else kwP[c] = pk.v;
      } else if (tid >= 896) {              // y-finalize(t-1) on idle waves 14,15
        if (t > 0) {
          const int c = tid - 896;
          float y = bout[c];
#pragma unroll
          for (int q = 0; q < 16; ++q) y += yP[q * 128 + c];
          out[((size_t)b * TSTEPS + (t - 1)) * DIN + c] = y;
        }
      }
      bar_lds();
    }

    // ==== Seg 6 (A): dots + norm + exp fused; bf16 keys; SR/SW via atomic ====
    {
      const float kn_r = sqrtf(sP[0]);
      const float kn_w = sqrtf(sP[1]);
      const float beta_r = sP[80], beta_w = sP[86];
      const int n = tid >> 1, hf = tid & 1;
      const int sw = (n >> 2) & 3;
      float dr = 0.f, dw = 0.f, ss = 0.f;
#pragma unroll
      for (int c = 0; c < 8; ++c) {
        const int cl = hf * 8 + c;
        const uint4 mv = memv[n * 16 + (cl ^ sw)];
        const uint4 kr = krP[cl];
        const uint4 kw = kwP[cl];
        const unsigned mw_[4] = { mv.x, mv.y, mv.z, mv.w };
        const unsigned krw[4] = { kr.x, kr.y, kr.z, kr.w };
        const unsigned kww[4] = { kw.x, kw.y, kw.z, kw.w };
#pragma unroll
        for (int j = 0; j < 4; ++j) {
          const float m0 = bf_lo(mw_[j]), m1 = bf_hi(mw_[j]);
          dr = fmaf(m0, bf_lo(krw[j]), dr); dr = fmaf(m1, bf_hi(krw[j]), dr);
          dw = fmaf(m0, bf_lo(kww[j]), dw); dw = fmaf(m1, bf_hi(kww[j]), dw);
          ss = fmaf(m0, m0, ss);            ss = fmaf(m1, m1, ss);
        }
      }
      dr += __shfl_xor(dr, 1);
      dw += __shfl_xor(dw, 1);
      ss += __shfl_xor(ss, 1);
      const float nr = sqrtf(ss);
      const float er = __expf(beta_r * dr / (nr * kn_r + EPSF));
      const float ew = __expf(beta_w * dw / (nr * kn_w + EPSF));
      if (hf == 0) { eR[n] = er; eW[n] = ew; }
      float s1_ = waveSum(er) * 0.5f;
      float s2_ = waveSum(ew) * 0.5f;
      if (lane == 0) { atomicAdd(&sP[2], s1_); atomicAdd(&sP[3], s2_); }
      bar_lds();
    }

    // ==== Seg 7: alpha (tid<512) + Y-top GEMV rows 0..127 (upper waves) ====
    {
      if (tid < NSLOT) {
        const float invE = 1.0f / sP[2];
        const float gr = sP[81], omg = 1.0f - sP[81];
        const int im = (tid - 1) & 511, ip = (tid + 1) & 511;
        const float wgm = gr * (eR[im] * invE) + omg * sWprev[im];
        const float wg0 = gr * (eR[tid] * invE) + omg * sWprev[tid];
        const float wgp = gr * (eR[ip] * invE) + omg * sWprev[ip];
        const float wt = sP[82] * wgp + sP[83] * wg0 + sP[84] * wgm;
        float p1 = (wt > 0.0f) ? __expf(sP[85] * __logf(wt)) : 0.0f;
        float P = waveSum(p1);
        sP1[tid] = p1;
        if (lane == 0) atomicAdd(&sP[4], P);
      } else {
        float4 acc = make_float4(0.f, 0.f, 0.f, 0.f);
        const float4 ha = *(const float4*)(sH + 8 * slT);
        const float4 hb = *(const float4*)(sH + 8 * slT + 4);
        const float hv[8] = { ha.x, ha.y, ha.z, ha.w, hb.x, hb.y, hb.z, hb.w };
#pragma unroll
        for (int w = 0; w < 8; ++w) {
          acc.x = fmaf(hv[w], wtop[w].x, acc.x); acc.y = fmaf(hv[w], wtop[w].y, acc.y);
          acc.z = fmaf(hv[w], wtop[w].z, acc.z); acc.w = fmaf(hv[w], wtop[w].w, acc.w);
        }
        *(float4*)(yP + slT * 128 + j4T) = acc;
      }
      bar_lds();
    }
    // ==== Seg 8: beta (tid<512, issues wbot prefetch) + x prefetch ====
    {
      if (tid < NSLOT) {
#pragma unroll
        for (int w = 0; w < 8; ++w)       // Seg11's Wout rows, issued early
          wbot[w] = *(const float4*)(Wout + (128 + 8 * slB + w) * DIN + j4B);
        const float pinv1 = 1.0f / (sP[4] + EPSF);
        const float invE = 1.0f / sP[3];
        const float gw = sP[87], omg = 1.0f - sP[87];
        const int im = (tid - 1) & 511, ip = (tid + 1) & 511;
        const float wgm = gw * (eW[im] * invE) + omg * (sP1[im] * pinv1);
        const float wg0 = gw * (eW[tid] * invE) + omg * (sP1[tid] * pinv1);
        const float wgp = gw * (eW[ip] * invE) + omg * (sP1[ip] * pinv1);
        sWr[tid] = sP1[tid] * pinv1;
        const float wt = sP[88] * wgp + sP[89] * wg0 + sP[90] * wgm;
        float p2 = (wt > 0.0f) ? __expf(sP[91] * __logf(wt)) : 0.0f;
        float P = waveSum(p2);
        U[tid] = p2;                       // raw p2 (eR region, dead)
        if (lane == 0) atomicAdd(&sP[5], P);
      } else if (tid < 512 + DIN && t + 1 < TSTEPS) {
        const int i = tid - 512;
        sXt[i] = x[((size_t)b * TSTEPS + (t + 1)) * DIN + i];
      }
      bar_lds();
    }

    // ==== Seg 9 (B): w_w inline; r-sweep + mem update; r via ds_add into sR;
    //      issues next step's w1 prefetch before the barrier ====
    {
      const float pinv2 = 1.0f / (sP[5] + EPSF);
      if (tid < NSLOT) sWprev[tid] = U[tid] * pinv2;   // next step's w_prev

      const int cl = l ^ ((g >> 2) & 3);
      float4 e4a = *(const float4*)(sOw + 136 + cl * 8);
      float4 e4b = *(const float4*)(sOw + 140 + cl * 8);
      float4 a4a = *(const float4*)(sOw + 264 + cl * 8);
      float4 a4b = *(const float4*)(sOw + 268 + cl * 8);
      const float e8[8] = { e4a.x, e4a.y, e4a.z, e4a.w, e4b.x, e4b.y, e4b.z, e4b.w };
      const float a8[8] = { a4a.x, a4a.y, a4a.z, a4a.w, a4b.x, a4b.y, a4b.z, a4b.w };
      float r8[8] = { 0, 0, 0, 0, 0, 0, 0, 0 };
#pragma unroll 2
      for (int it = 0; it < 8; ++it) {
        const int n = g + 64 * it;
        const float wrn = sWr[n];
        const float wwn = U[n] * pinv2;
        uint4 pk = memv[n * 16 + l];
        const unsigned wds[4] = { pk.x, pk.y, pk.z, pk.w };
        float m[8];
#pragma unroll
        for (int j = 0; j < 4; ++j) { m[2 * j] = bf_lo(wds[j]); m[2 * j + 1] = bf_hi(wds[j]); }
#pragma unroll
        for (int j = 0; j < 8; ++j) {
          r8[j] = fmaf(wrn, m[j], r8[j]);
          const float d = fmaf(-e8[j], m[j], a8[j]);
          m[j] = fmaf(wwn, d, m[j]);
        }
        pk.x = pkbf(m[0], m[1]);
        pk.y = pkbf(m[2], m[3]);
        pk.z = pkbf(m[4], m[5]);
        pk.w = pkbf(m[6], m[7]);
        memv[n * 16 + l] = pk;
      }
#pragma unroll
      for (int j = 0; j < 8; ++j) {          // partners g^1,g^2 share chunk
        r8[j] += __shfl_xor(r8[j], 16);
        r8[j] += __shfl_xor(r8[j], 32);
      }
      if (lane < 16) {                       // 16 waves x 8 ds_add into sR
#pragma unroll
        for (int j = 0; j < 8; ++j) atomicAdd(&sR[cl * 8 + j], r8[j]);
      }
      LOAD_W1();                             // next step's Seg1 panel in flight
      bar_lds();
    }

    // ==== Seg 11: Y-bottom GEMV rows 128..255 (tid<512), accumulate into yP ====
    {
      if (tid < 512) {
        float4 acc = *(const float4*)(yP + slB * 128 + j4B);
        const float4 ra = *(const float4*)(sR + 8 * slB);
        const float4 rb = *(const float4*)(sR + 8 * slB + 4);
        const float rv[8] = { ra.x, ra.y, ra.z, ra.w, rb.x, rb.y, rb.z, rb.w };
#pragma unroll
        for (int w = 0; w < 8; ++w) {
          acc.x = fmaf(rv[w], wbot[w].x, acc.x); acc.y = fmaf(rv[w], wbot[w].y, acc.y);
          acc.z = fmaf(rv[w], wbot[w].z, acc.z); acc.w = fmaf(rv[w], wbot[w].w, acc.w);
        }
        *(float4*)(yP + slB * 128 + j4B) = acc;
      }
      bar_lds();
    }
  }

  // final y
  if (tid < DIN) {
    float y = bout[tid];
#pragma unroll
    for (int q = 0; q < 16; ++q) y += yP[q * 128 + tid];
    out[((size_t)b * TSTEPS + (TSTEPS - 1)) * DIN + tid] = y;
  }
}

extern "C" void kernel_launch(void* const* d_in, const int* in_sizes, int n_in,
                              void* d_out, int out_size, void* d_ws, size_t ws_size,
                              hipStream_t stream) {
  (void)in_sizes; (void)n_in; (void)out_size; (void)d_ws; (void)ws_size;
  hipFuncSetAttribute(reinterpret_cast<const void*>(ntm_kernel),
                      hipFuncAttributeMaxDynamicSharedMemorySize, (int)LDS_BYTES);
  ntm_kernel<<<dim3(BSZ), dim3(NT), LDS_BYTES, stream>>>(
      (const float*)d_in[0], (const float*)d_in[1], (const float*)d_in[2],
      (const float*)d_in[3], (const float*)d_in[4], (const float*)d_in[5],
      (const float*)d_in[6], (const float*)d_in[7], (const float*)d_in[8],
      (const float*)d_in[9], (const float*)d_in[10],
      (float*)d_out);
}

// Round 2
// 2052.805 us; speedup vs baseline: 1.0044x; 1.0044x over previous
//
#include <hip/hip_runtime.h>
#include <hip/hip_bf16.h>
#include <math.h>

#define NT 1024
#define BSZ 128
#define TSTEPS 32
#define DIN 128
#define DHH 128
#define NSLOT 512
#define EPSF 1e-8f

// LDS: [0,131072) mem bf16[512][128] XOR-swizzled; then float scratch F[7160]
static constexpr int F_FLOATS = 7160;
static constexpr size_t LDS_BYTES = 131072 + F_FLOATS * sizeof(float);

__device__ __forceinline__ float bf_lo(unsigned u) {
  union { unsigned u; float f; } c; c.u = u << 16; return c.f;
}
__device__ __forceinline__ float bf_hi(unsigned u) {
  union { unsigned u; float f; } c; c.u = u & 0xffff0000u; return c.f;
}
__device__ __forceinline__ unsigned short f2us(float f) {
  union { unsigned short s; __hip_bfloat16 h; } c; c.h = __float2bfloat16(f); return c.s;
}
__device__ __forceinline__ unsigned pkbf(float a, float b) {
  union { __hip_bfloat162 h2; unsigned u; } c;
  c.h2 = __float22bfloat162_rn(make_float2(a, b));
  return c.u;
}
__device__ __forceinline__ float sigmoid_(float x) { return 1.0f / (1.0f + __expf(-x)); }
__device__ __forceinline__ float softplus_(float x) {
  return fmaxf(x, 0.0f) + log1pf(__expf(-fabsf(x)));
}
__device__ __forceinline__ float tanh_(float x) {
  float e = __expf(-2.0f * fabsf(x));
  float t = (1.0f - e) / (1.0f + e);
  return copysignf(t, x);
}
__device__ __forceinline__ float waveSum(float v) {
#pragma unroll
  for (int m = 32; m >= 1; m >>= 1) v += __shfl_xor(v, m);
  return v;
}

// LDS-only barrier: does NOT drain vmcnt, so in-flight global loads/stores
// survive the barrier. All inter-thread traffic in this kernel is LDS (out is
// write-only), so lgkmcnt(0)+s_barrier gives full __syncthreads semantics here.
__device__ __forceinline__ void bar_lds() {
  asm volatile("s_waitcnt lgkmcnt(0)" ::: "memory");
  __builtin_amdgcn_s_barrier();
}

// One block (1024 threads) per batch element; all 32 steps in-block.
// mem in LDS, rows XOR-swizzled: stored uint4 slot u = c ^ ((n>>2)&3).
// Base = r15-lineage 810us kernel. R1 spilled (cross-barrier panels 96+ VGPR
// -> scratch, 2.5GB fetch). R2 keeps the theory, bounds the registers:
//   A. bar_lds everywhere in-loop (no vmcnt drain at barriers).
//   B. b128 LDS vectorization: V[384]=[x|h|r] contiguous, float4 reads in
//      Seg1/3/7/11 (DS-pipe relief, zero register cost).
//   C. In-segment load batching: Seg1 all-24-then-FMA (48 VGPR transient);
//      Seg3 two 16-batches staggered with FMA (<=64 in flight). One L2
//      latency exposure per batch instead of unroll-8's 4 waits.
//   D. Only two cross-barrier panels, each 32 VGPR and one barrier deep,
//      time-disjoint: wtop (SegF->Seg7), wbot (Seg8->Seg11). NO w1/w3
//      cross-barrier arrays (that was the R1 spill).
__global__ __launch_bounds__(NT, 4)
void ntm_kernel(const float* __restrict__ x,
                const float* __restrict__ Wxh,
                const float* __restrict__ Whh,
                const float* __restrict__ Wrh,
                const float* __restrict__ bh,
                const float* __restrict__ Wout,
                const float* __restrict__ bout,
                const float* __restrict__ Wr,
                const float* __restrict__ br,
                const float* __restrict__ Ww,
                const float* __restrict__ bw,
                float* __restrict__ out)
{
  extern __shared__ char smem[];
  uint4* memv = (uint4*)smem;              // bf16 mem, row n = 16 uint4 (swizzled)
  float* F = (float*)(smem + 131072);

  const int b = blockIdx.x;
  const int tid = threadIdx.x;
  const int g = tid >> 4, l = tid & 15;    // Phase-B mapping
  const int lane = tid & 63, wid = tid >> 6;

  float* U      = F + 0;      // 2560 multi-use: O/H partials (incl. [2096..2191]
                              //      half-slot partials); eR/eW; p2raw
  float* yP     = F + 2560;   // 2048 Y partials (live across step boundary)
  float* sWprev = F + 4608;   // 512
  float* sWr    = F + 5120;   // 512
  float* sP1    = F + 5632;   // 512 p1; aliased early by krP/kwP packed keys
  float* sOr    = F + 6144;   // 144 (134 used)
  float* sOw    = F + 6288;   // 392: [0..127] k_w, [136..263] e (16B-aligned), [264..391] a
  float* sXt    = F + 6680;   // 128  } contiguous V[384] = [x | h | r]
  float* sH     = F + 6808;   // 128  }  (order matters for Seg1 float4 reads)
  float* sR     = F + 6936;   // 128  }  (ds_add target in Seg 9)
  float* sP     = F + 7064;   // 96: [0]kr2 [1]kw2 [2]SR [3]SW [4]P1 [5]P2; [80..91] scalars
  float* V      = sXt;        // V[i]: i<128 x, i<256 h, else r
  uint4* krP    = (uint4*)(sP1 + 0);
  uint4* kwP    = (uint4*)(sP1 + 64);
  float* eR     = U + 0;
  float* eW     = U + 512;

  // ---- persistent per-thread indices (loop-invariant) ----
  const int s1  = tid >> 6;                 // Seg1 row-seg (== wid)
  const int j2s = (tid & 63) * 2;           // Seg1 col pair
  const int i0s = s1 * 24;                  // Seg1 row base
  const int q3  = (tid >= 786) ? 3 : (tid >= 524) ? 2 : (tid >= 262) ? 1 : 0;
  const int P3  = tid - 262 * q3;
  const int i03 = 32 * q3;
  const float2* p3base;
  int stride3;
  if (P3 < 67) { p3base = (const float2*)(Wr + i03 * 134 + 2 * P3); stride3 = 67; }
  else         { p3base = (const float2*)(Ww + i03 * 390 + 2 * (P3 - 67)); stride3 = 195; }
  const int hs   = wid * 3 + lane;          // half-slot id (valid when lane<3)
  const int i0h  = 96 + 16 * (hs & 1);
  const int cph2 = 2 * (171 + (hs >> 1));
  const int pT  = tid - 512;                // Seg7 upper mapping (tid>=512)
  const int j4T = (pT & 31) * 4, slT = pT >> 5;
  const int j4B = (tid & 31) * 4, slB = tid >> 5;  // Seg11 mapping (tid<512)

  // ---- init ----
  {
    const unsigned short mb = f2us(1e-6f);
    const unsigned w32 = ((unsigned)mb << 16) | mb;
    const uint4 fv = make_uint4(w32, w32, w32, w32);
    for (int i = tid; i < NSLOT * DHH / 8; i += NT) memv[i] = fv;
  }
  for (int i = tid; i < NSLOT; i += NT) sWprev[i] = 1.0f / NSLOT;
  if (tid < DHH) { sH[tid] = 0.0f; sR[tid] = 0.0f; }
  if (tid < DIN) sXt[tid] = x[(size_t)b * TSTEPS * DIN + tid];
  __syncthreads();

  for (int t = 0; t < TSTEPS; ++t) {
    float4 wtop[8];   // Wout rows 0..127   (issued SegF-top, used Seg7)
    float4 wbot[8];   // Wout rows 128..255 (issued Seg8-top, used Seg11)

    // ==== Seg 1: H partials — batch all 24 weight loads, then FMA ====
    {
      float2 w1[24];
#pragma unroll
      for (int w = 0; w < 24; ++w) {
        const int i = i0s + w;
        const float* Wp = (i < 128) ? (Wxh + i * DHH)
                        : (i < 256) ? (Whh + (i - 128) * DHH)
                                    : (Wrh + (i - 256) * DHH);
        w1[w] = *(const float2*)(Wp + j2s);
      }
      float2 acc = make_float2(0.f, 0.f);
#pragma unroll
      for (int k = 0; k < 6; ++k) {
        const float4 vv = *(const float4*)(V + i0s + 4 * k);
        const float vk[4] = { vv.x, vv.y, vv.z, vv.w };
#pragma unroll
        for (int u = 0; u < 4; ++u) {
          acc.x = fmaf(vk[u], w1[4 * k + u].x, acc.x);
          acc.y = fmaf(vk[u], w1[4 * k + u].y, acc.y);
        }
      }
      *(float2*)(U + s1 * 128 + j2s) = acc;
      bar_lds();
    }
    // ==== Seg 2: h = tanh(sum + bh) ====
    if (tid < DHH) {
      float a2 = bh[tid];
#pragma unroll
      for (int q2 = 0; q2 < 16; ++q2) a2 += U[q2 * 128 + tid];
      sH[tid] = tanh_(a2);
    }
    bar_lds();

    // ==== Seg 3: O partials — staged 16-load batches; halfslot interleaved ====
    {
      float2 wvA[16], wvB[16], w3h[16];
#pragma unroll
      for (int w = 0; w < 16; ++w) wvA[w] = p3base[w * stride3];
#pragma unroll
      for (int w = 0; w < 16; ++w) wvB[w] = p3base[(16 + w) * stride3];
      float2 acc = make_float2(0.f, 0.f);
#pragma unroll
      for (int k = 0; k < 4; ++k) {         // rows i03 .. i03+15 (wvA)
        const float4 hv = *(const float4*)(sH + i03 + 4 * k);
        const float hk[4] = { hv.x, hv.y, hv.z, hv.w };
#pragma unroll
        for (int u = 0; u < 4; ++u) {
          acc.x = fmaf(hk[u], wvA[4 * k + u].x, acc.x);
          acc.y = fmaf(hk[u], wvA[4 * k + u].y, acc.y);
        }
      }
      if (lane < 3) {                       // halfslot loads in flight over FMA-B
#pragma unroll
        for (int w = 0; w < 16; ++w)
          w3h[w] = *(const float2*)(Ww + (i0h + w) * 390 + cph2);
      }
#pragma unroll
      for (int k = 0; k < 4; ++k) {         // rows i03+16 .. i03+31 (wvB)
        const float4 hv = *(const float4*)(sH + i03 + 16 + 4 * k);
        const float hk[4] = { hv.x, hv.y, hv.z, hv.w };
#pragma unroll
        for (int u = 0; u < 4; ++u) {
          acc.x = fmaf(hk[u], wvB[4 * k + u].x, acc.x);
          acc.y = fmaf(hk[u], wvB[4 * k + u].y, acc.y);
        }
      }
      *(float2*)(U + tid * 2) = acc;
      if (lane < 3) {                       // 48 half-slots, 3 per wave
        float2 acch = make_float2(0.f, 0.f);
#pragma unroll
        for (int k = 0; k < 4; ++k) {
          const float4 hv = *(const float4*)(sH + i0h + 4 * k);
          const float hk[4] = { hv.x, hv.y, hv.z, hv.w };
#pragma unroll
          for (int u = 0; u < 4; ++u) {
            acch.x = fmaf(hk[u], w3h[4 * k + u].x, acch.x);
            acch.y = fmaf(hk[u], w3h[4 * k + u].y, acch.y);
          }
        }
        U[2096 + hs * 2]     = acch.x;
        U[2096 + hs * 2 + 1] = acch.y;
      }
      if (tid == 1023) {
        sP[0] = 0.f; sP[1] = 0.f; sP[2] = 0.f; sP[3] = 0.f; sP[4] = 0.f; sP[5] = 0.f;
      }
      bar_lds();
    }

    // ==== Seg F: fused combine+bias / knorm / e,a transforms / key packing /
    //      head scalars / sR zeroing / y-finalize(t-1); issues wtop prefetch ====
    {
      if (tid >= 512) {                     // Seg7's Wout rows, issued early
#pragma unroll
        for (int w = 0; w < 8; ++w)
          wtop[w] = *(const float4*)(Wout + (8 * slT + w) * DIN + j4T);
      }
      if (tid < 134) {                      // o_r col tid
        float v = 0.f;
#pragma unroll
        for (int q = 0; q < 4; ++q) v += U[tid + 524 * q];
        v += br[tid];
        sOr[tid] = v;
        if (tid < 128) {                    // waves 0,1 whole: |k_r|^2
          float s2 = waveSum(v * v);
          if (lane == 0) atomicAdd(&sP[0], s2);
        }
      } else if (tid == 134) {              // read-head scalars from U directly
        float sc[6];
#pragma unroll
        for (int j = 0; j < 6; ++j) {
          float v = 0.f;
#pragma unroll
          for (int q = 0; q < 4; ++q) v += U[(128 + j) + 524 * q];
          sc[j] = v + br[128 + j];
        }
        sP[80] = softplus_(sc[0]);
        sP[81] = sigmoid_(sc[1]);
        float mx = fmaxf(sc[2], fmaxf(sc[3], sc[4]));
        float e0 = __expf(sc[2] - mx), e1 = __expf(sc[3] - mx), e2 = __expf(sc[4] - mx);
        float es = e0 + e1 + e2;
        sP[82] = e0 / es; sP[83] = e1 / es; sP[84] = e2 / es;
        sP[85] = 1.0f + softplus_(sc[5]);
      } else if (tid == 135) {              // write-head scalars (o_w cols 128..133)
        float sc[6];
#pragma unroll
        for (int j = 0; j < 6; ++j) {
          float v = 0.f;
#pragma unroll
          for (int q = 0; q < 4; ++q) v += U[(262 + j) + 524 * q];
          sc[j] = v + bw[128 + j];
        }
        sP[86] = softplus_(sc[0]);
        sP[87] = sigmoid_(sc[1]);
        float mx = fmaxf(sc[2], fmaxf(sc[3], sc[4]));
        float e0 = __expf(sc[2] - mx), e1 = __expf(sc[3] - mx), e2 = __expf(sc[4] - mx);
        float es = e0 + e1 + e2;
        sP[88] = e0 / es; sP[89] = e1 / es; sP[90] = e2 / es;
        sP[91] = 1.0f + softplus_(sc[5]);
      } else if (tid >= 256 && tid < 512) { // e (256..383) / a (384..511)
        const int cc = tid + 12;            // combined col = 134 + cw, cw = tid-122
        float v = U[cc] + U[cc + 524] + U[cc + 1048];
        if (cc < 476) {
          v += U[cc + 1572];
        } else {                            // q=3 partial split into 2 halves
          const int cw = cc - 134;          // 342..389
          const int e = (cw >> 1) - 171;    // 0..23
          const int base = 2096 + 4 * e + (cw & 1);
          v += U[base] + U[base + 2];
        }
        v += bw[tid - 122];
        sOw[tid - 120] = (tid < 384) ? sigmoid_(v) : tanh_(v);
      } else if (tid >= 512 && tid < 640) { // k_w col cw (waves 8,9 whole): |k_w|^2
        const int cw = tid - 512;
        float v = 0.f;
#pragma unroll
        for (int q = 0; q < 4; ++q) v += U[(134 + cw) + 524 * q];
        v += bw[cw];
        sOw[cw] = v;
        float s2 = waveSum(v * v);
        if (lane == 0) atomicAdd(&sP[1], s2);
      } else if (tid >= 640 && tid < 768) {
        sR[tid - 640] = 0.f;                // Seg-9 ds_add target
      } else if (tid >= 768 && tid < 800) { // bf16 key packing from U (redundant combine)
        const int t2 = tid - 768;
        const int c = t2 & 15;
        union { uint4 v; unsigned short h[8]; } pk;
#pragma unroll
        for (int j = 0; j < 8; ++j) {
          const int col = c * 8 + j;        // 0..127
          float v = 0.f;
#pragma unroll
          for (int q = 0; q < 4; ++q)
            v += U[((t2 < 16) ? col : (134 + col)) + 524 * q];
          v += (t2 < 16) ? br[col] : bw[col];
          pk.h[j] = f2us(v);
        }
        if (t2 < 16) krP[c] = pk.v; else kwP[c] = pk.v;
      } else if (tid >= 896) {              // y-finalize(t-1) on idle waves 14,15
        if (t > 0) {
          const int c = tid - 896;
          float y = bout[c];
#pragma unroll
          for (int q = 0; q < 16; ++q) y += yP[q * 128 + c];
          out[((size_t)b * TSTEPS + (t - 1)) * DIN + c] = y;
        }
      }
      bar_lds();
    }

    // ==== Seg 6 (A): dots + norm + exp fused; bf16 keys; SR/SW via atomic ====
    {
      const float kn_r = sqrtf(sP[0]);
      const float kn_w = sqrtf(sP[1]);
      const float beta_r = sP[80], beta_w = sP[86];
      const int n = tid >> 1, hf = tid & 1;
      const int sw = (n >> 2) & 3;
      float dr = 0.f, dw = 0.f, ss = 0.f;
#pragma unroll
      for (int c = 0; c < 8; ++c) {
        const int cl = hf * 8 + c;
        const uint4 mv = memv[n * 16 + (cl ^ sw)];
        const uint4 kr = krP[cl];
        const uint4 kw = kwP[cl];
        const unsigned mw_[4] = { mv.x, mv.y, mv.z, mv.w };
        const unsigned krw[4] = { kr.x, kr.y, kr.z, kr.w };
        const unsigned kww[4] = { kw.x, kw.y, kw.z, kw.w };
#pragma unroll
        for (int j = 0; j < 4; ++j) {
          const float m0 = bf_lo(mw_[j]), m1 = bf_hi(mw_[j]);
          dr = fmaf(m0, bf_lo(krw[j]), dr); dr = fmaf(m1, bf_hi(krw[j]), dr);
          dw = fmaf(m0, bf_lo(kww[j]), dw); dw = fmaf(m1, bf_hi(kww[j]), dw);
          ss = fmaf(m0, m0, ss);            ss = fmaf(m1, m1, ss);
        }
      }
      dr += __shfl_xor(dr, 1);
      dw += __shfl_xor(dw, 1);
      ss += __shfl_xor(ss, 1);
      const float nr = sqrtf(ss);
      const float er = __expf(beta_r * dr / (nr * kn_r + EPSF));
      const float ew = __expf(beta_w * dw / (nr * kn_w + EPSF));
      if (hf == 0) { eR[n] = er; eW[n] = ew; }
      float s1_ = waveSum(er) * 0.5f;
      float s2_ = waveSum(ew) * 0.5f;
      if (lane == 0) { atomicAdd(&sP[2], s1_); atomicAdd(&sP[3], s2_); }
      bar_lds();
    }

    // ==== Seg 7: alpha (tid<512) + Y-top GEMV rows 0..127 (upper waves) ====
    {
      if (tid < NSLOT) {
        const float invE = 1.0f / sP[2];
        const float gr = sP[81], omg = 1.0f - sP[81];
        const int im = (tid - 1) & 511, ip = (tid + 1) & 511;
        const float wgm = gr * (eR[im] * invE) + omg * sWprev[im];
        const float wg0 = gr * (eR[tid] * invE) + omg * sWprev[tid];
        const float wgp = gr * (eR[ip] * invE) + omg * sWprev[ip];
        const float wt = sP[82] * wgp + sP[83] * wg0 + sP[84] * wgm;
        float p1 = (wt > 0.0f) ? __expf(sP[85] * __logf(wt)) : 0.0f;
        float P = waveSum(p1);
        sP1[tid] = p1;
        if (lane == 0) atomicAdd(&sP[4], P);
      } else {
        float4 acc = make_float4(0.f, 0.f, 0.f, 0.f);
        const float4 ha = *(const float4*)(sH + 8 * slT);
        const float4 hb = *(const float4*)(sH + 8 * slT + 4);
        const float hv[8] = { ha.x, ha.y, ha.z, ha.w, hb.x, hb.y, hb.z, hb.w };
#pragma unroll
        for (int w = 0; w < 8; ++w) {
          acc.x = fmaf(hv[w], wtop[w].x, acc.x); acc.y = fmaf(hv[w], wtop[w].y, acc.y);
          acc.z = fmaf(hv[w], wtop[w].z, acc.z); acc.w = fmaf(hv[w], wtop[w].w, acc.w);
        }
        *(float4*)(yP + slT * 128 + j4T) = acc;
      }
      bar_lds();
    }
    // ==== Seg 8: beta (tid<512, issues wbot prefetch) + x prefetch ====
    {
      if (tid < NSLOT) {
#pragma unroll
        for (int w = 0; w < 8; ++w)       // Seg11's Wout rows, issued early
          wbot[w] = *(const float4*)(Wout + (128 + 8 * slB + w) * DIN + j4B);
        const float pinv1 = 1.0f / (sP[4] + EPSF);
        const float invE = 1.0f / sP[3];
        const float gw = sP[87], omg = 1.0f - sP[87];
        const int im = (tid - 1) & 511, ip = (tid + 1) & 511;
        const float wgm = gw * (eW[im] * invE) + omg * (sP1[im] * pinv1);
        const float wg0 = gw * (eW[tid] * invE) + omg * (sP1[tid] * pinv1);
        const float wgp = gw * (eW[ip] * invE) + omg * (sP1[ip] * pinv1);
        sWr[tid] = sP1[tid] * pinv1;
        const float wt = sP[88] * wgp + sP[89] * wg0 + sP[90] * wgm;
        float p2 = (wt > 0.0f) ? __expf(sP[91] * __logf(wt)) : 0.0f;
        float P = waveSum(p2);
        U[tid] = p2;                       // raw p2 (eR region, dead)
        if (lane == 0) atomicAdd(&sP[5], P);
      } else if (tid < 512 + DIN && t + 1 < TSTEPS) {
        const int i = tid - 512;
        sXt[i] = x[((size_t)b * TSTEPS + (t + 1)) * DIN + i];
      }
      bar_lds();
    }

    // ==== Seg 9 (B): w_w inline; r-sweep + mem update; r via ds_add into sR ====
    {
      const float pinv2 = 1.0f / (sP[5] + EPSF);
      if (tid < NSLOT) sWprev[tid] = U[tid] * pinv2;   // next step's w_prev

      const int cl = l ^ ((g >> 2) & 3);
      float4 e4a = *(const float4*)(sOw + 136 + cl * 8);
      float4 e4b = *(const float4*)(sOw + 140 + cl * 8);
      float4 a4a = *(const float4*)(sOw + 264 + cl * 8);
      float4 a4b = *(const float4*)(sOw + 268 + cl * 8);
      const float e8[8] = { e4a.x, e4a.y, e4a.z, e4a.w, e4b.x, e4b.y, e4b.z, e4b.w };
      const float a8[8] = { a4a.x, a4a.y, a4a.z, a4a.w, a4b.x, a4b.y, a4b.z, a4b.w };
      float r8[8] = { 0, 0, 0, 0, 0, 0, 0, 0 };
#pragma unroll 2
      for (int it = 0; it < 8; ++it) {
        const int n = g + 64 * it;
        const float wrn = sWr[n];
        const float wwn = U[n] * pinv2;
        uint4 pk = memv[n * 16 + l];
        const unsigned wds[4] = { pk.x, pk.y, pk.z, pk.w };
        float m[8];
#pragma unroll
        for (int j = 0; j < 4; ++j) { m[2 * j] = bf_lo(wds[j]); m[2 * j + 1] = bf_hi(wds[j]); }
#pragma unroll
        for (int j = 0; j < 8; ++j) {
          r8[j] = fmaf(wrn, m[j], r8[j]);
          const float d = fmaf(-e8[j], m[j], a8[j]);
          m[j] = fmaf(wwn, d, m[j]);
        }
        pk.x = pkbf(m[0], m[1]);
        pk.y = pkbf(m[2], m[3]);
        pk.z = pkbf(m[4], m[5]);
        pk.w = pkbf(m[6], m[7]);
        memv[n * 16 + l] = pk;
      }
#pragma unroll
      for (int j = 0; j < 8; ++j) {          // partners g^1,g^2 share chunk
        r8[j] += __shfl_xor(r8[j], 16);
        r8[j] += __shfl_xor(r8[j], 32);
      }
      if (lane < 16) {                       // 16 waves x 8 ds_add into sR
#pragma unroll
        for (int j = 0; j < 8; ++j) atomicAdd(&sR[cl * 8 + j], r8[j]);
      }
      bar_lds();
    }

    // ==== Seg 11: Y-bottom GEMV rows 128..255 (tid<512), accumulate into yP ====
    {
      if (tid < 512) {
        float4 acc = *(const float4*)(yP + slB * 128 + j4B);
        const float4 ra = *(const float4*)(sR + 8 * slB);
        const float4 rb = *(const float4*)(sR + 8 * slB + 4);
        const float rv[8] = { ra.x, ra.y, ra.z, ra.w, rb.x, rb.y, rb.z, rb.w };
#pragma unroll
        for (int w = 0; w < 8; ++w) {
          acc.x = fmaf(rv[w], wbot[w].x, acc.x); acc.y = fmaf(rv[w], wbot[w].y, acc.y);
          acc.z = fmaf(rv[w], wbot[w].z, acc.z); acc.w = fmaf(rv[w], wbot[w].w, acc.w);
        }
        *(float4*)(yP + slB * 128 + j4B) = acc;
      }
      bar_lds();
    }
  }

  // final y
  if (tid < DIN) {
    float y = bout[tid];
#pragma unroll
    for (int q = 0; q < 16; ++q) y += yP[q * 128 + tid];
    out[((size_t)b * TSTEPS + (TSTEPS - 1)) * DIN + tid] = y;
  }
}

extern "C" void kernel_launch(void* const* d_in, const int* in_sizes, int n_in,
                              void* d_out, int out_size, void* d_ws, size_t ws_size,
                              hipStream_t stream) {
  (void)in_sizes; (void)n_in; (void)out_size; (void)d_ws; (void)ws_size;
  hipFuncSetAttribute(reinterpret_cast<const void*>(ntm_kernel),
                      hipFuncAttributeMaxDynamicSharedMemorySize, (int)LDS_BYTES);
  ntm_kernel<<<dim3(BSZ), dim3(NT), LDS_BYTES, stream>>>(
      (const float*)d_in[0], (const float*)d_in[1], (const float*)d_in[2],
      (const float*)d_in[3], (const float*)d_in[4], (const float*)d_in[5],
      (const float*)d_in[6], (const float*)d_in[7], (const float*)d_in[8],
      (const float*)d_in[9], (const float*)d_in[10],
      (float*)d_out);
}

// Round 3
// 2034.876 us; speedup vs baseline: 1.0132x; 1.0088x over previous
//
#include <hip/hip_runtime.h>
#include <hip/hip_bf16.h>
#include <math.h>

#define NT 1024
#define BSZ 128
#define TSTEPS 32
#define DIN 128
#define DHH 128
#define NSLOT 512
#define EPSF 1e-8f

// LDS: [0,131072) mem bf16[512][128] XOR-swizzled; then float scratch F[7160]
static constexpr int F_FLOATS = 7160;
static constexpr size_t LDS_BYTES = 131072 + F_FLOATS * sizeof(float);

__device__ __forceinline__ float bf_lo(unsigned u) {
  union { unsigned u; float f; } c; c.u = u << 16; return c.f;
}
__device__ __forceinline__ float bf_hi(unsigned u) {
  union { unsigned u; float f; } c; c.u = u & 0xffff0000u; return c.f;
}
__device__ __forceinline__ unsigned short f2us(float f) {
  union { unsigned short s; __hip_bfloat16 h; } c; c.h = __float2bfloat16(f); return c.s;
}
__device__ __forceinline__ unsigned pkbf(float a, float b) {
  union { __hip_bfloat162 h2; unsigned u; } c;
  c.h2 = __float22bfloat162_rn(make_float2(a, b));
  return c.u;
}
__device__ __forceinline__ float sigmoid_(float x) { return 1.0f / (1.0f + __expf(-x)); }
__device__ __forceinline__ float softplus_(float x) {
  return fmaxf(x, 0.0f) + log1pf(__expf(-fabsf(x)));
}
__device__ __forceinline__ float tanh_(float x) {
  float e = __expf(-2.0f * fabsf(x));
  float t = (1.0f - e) / (1.0f + e);
  return copysignf(t, x);
}
__device__ __forceinline__ float waveSum(float v) {
#pragma unroll
  for (int m = 32; m >= 1; m >>= 1) v += __shfl_xor(v, m);
  return v;
}

// LDS-only barrier: does NOT drain vmcnt, so in-flight global loads/stores
// survive the barrier. All inter-thread traffic in this kernel is LDS (out is
// write-only), so lgkmcnt(0)+s_barrier gives full __syncthreads semantics here.
__device__ __forceinline__ void bar_lds() {
  asm volatile("s_waitcnt lgkmcnt(0)" ::: "memory");
  __builtin_amdgcn_s_barrier();
}

// One block (1024 threads) per batch element; all 32 steps in-block.
// mem in LDS, rows XOR-swizzled: stored uint4 slot u = c ^ ((n>>2)&3).
// R1/R2 regression root cause: __launch_bounds__(1024,4) only sets a MIN
// waves/EU; the compiler targeted 8 waves/SIMD -> 64-VGPR budget (see
// VGPR_Count=64 in all rounds) and spilled every batched-load array to
// scratch (1.8GB fetch / 0.5GB write per dispatch). The 160KB dynamic LDS
// already caps the CU at 1 block = 4 waves/SIMD, so that occupancy target
// is unreachable. Fix: amdgpu_waves_per_eu(4,4) -> 128-VGPR budget.
// Mechanisms retained from R2 (now actually register-resident):
//   A. bar_lds everywhere in-loop (no vmcnt drain at barriers).
//   B. b128 LDS vectorization: V[384]=[x|h|r] contiguous, float4 reads in
//      Seg1/3/7/11 (DS-pipe relief).
//   C. In-segment load batching: Seg1 all-24-then-FMA; Seg3 two 16-batches
//      staggered with FMA. One L2 latency exposure per batch.
//   D. Two cross-barrier panels, 32 VGPR each, one barrier deep,
//      time-disjoint: wtop (SegF->Seg7), wbot (Seg8->Seg11).
__global__ __attribute__((amdgpu_flat_work_group_size(NT, NT), amdgpu_waves_per_eu(4, 4)))
void ntm_kernel(const float* __restrict__ x,
                const float* __restrict__ Wxh,
                const float* __restrict__ Whh,
                const float* __restrict__ Wrh,
                const float* __restrict__ bh,
                const float* __restrict__ Wout,
                const float* __restrict__ bout,
                const float* __restrict__ Wr,
                const float* __restrict__ br,
                const float* __restrict__ Ww,
                const float* __restrict__ bw,
                float* __restrict__ out)
{
  extern __shared__ char smem[];
  uint4* memv = (uint4*)smem;              // bf16 mem, row n = 16 uint4 (swizzled)
  float* F = (float*)(smem + 131072);

  const int b = blockIdx.x;
  const int tid = threadIdx.x;
  const int g = tid >> 4, l = tid & 15;    // Phase-B mapping
  const int lane = tid & 63, wid = tid >> 6;

  float* U      = F + 0;      // 2560 multi-use: O/H partials (incl. [2096..2191]
                              //      half-slot partials); eR/eW; p2raw
  float* yP     = F + 2560;   // 2048 Y partials (live across step boundary)
  float* sWprev = F + 4608;   // 512
  float* sWr    = F + 5120;   // 512
  float* sP1    = F + 5632;   // 512 p1; aliased early by krP/kwP packed keys
  float* sOr    = F + 6144;   // 144 (134 used)
  float* sOw    = F + 6288;   // 392: [0..127] k_w, [136..263] e (16B-aligned), [264..391] a
  float* sXt    = F + 6680;   // 128  } contiguous V[384] = [x | h | r]
  float* sH     = F + 6808;   // 128  }  (order matters for Seg1 float4 reads)
  float* sR     = F + 6936;   // 128  }  (ds_add target in Seg 9)
  float* sP     = F + 7064;   // 96: [0]kr2 [1]kw2 [2]SR [3]SW [4]P1 [5]P2; [80..91] scalars
  float* V      = sXt;        // V[i]: i<128 x, i<256 h, else r
  uint4* krP    = (uint4*)(sP1 + 0);
  uint4* kwP    = (uint4*)(sP1 + 64);
  float* eR     = U + 0;
  float* eW     = U + 512;

  // ---- persistent per-thread indices (loop-invariant) ----
  const int s1  = tid >> 6;                 // Seg1 row-seg (== wid)
  const int j2s = (tid & 63) * 2;           // Seg1 col pair
  const int i0s = s1 * 24;                  // Seg1 row base
  const int q3  = (tid >= 786) ? 3 : (tid >= 524) ? 2 : (tid >= 262) ? 1 : 0;
  const int P3  = tid - 262 * q3;
  const int i03 = 32 * q3;
  const float2* p3base;
  int stride3;
  if (P3 < 67) { p3base = (const float2*)(Wr + i03 * 134 + 2 * P3); stride3 = 67; }
  else         { p3base = (const float2*)(Ww + i03 * 390 + 2 * (P3 - 67)); stride3 = 195; }
  const int hs   = wid * 3 + lane;          // half-slot id (valid when lane<3)
  const int i0h  = 96 + 16 * (hs & 1);
  const int cph2 = 2 * (171 + (hs >> 1));
  const int pT  = tid - 512;                // Seg7 upper mapping (tid>=512)
  const int j4T = (pT & 31) * 4, slT = pT >> 5;
  const int j4B = (tid & 31) * 4, slB = tid >> 5;  // Seg11 mapping (tid<512)

  // ---- init ----
  {
    const unsigned short mb = f2us(1e-6f);
    const unsigned w32 = ((unsigned)mb << 16) | mb;
    const uint4 fv = make_uint4(w32, w32, w32, w32);
    for (int i = tid; i < NSLOT * DHH / 8; i += NT) memv[i] = fv;
  }
  for (int i = tid; i < NSLOT; i += NT) sWprev[i] = 1.0f / NSLOT;
  if (tid < DHH) { sH[tid] = 0.0f; sR[tid] = 0.0f; }
  if (tid < DIN) sXt[tid] = x[(size_t)b * TSTEPS * DIN + tid];
  __syncthreads();

  for (int t = 0; t < TSTEPS; ++t) {
    float4 wtop[8];   // Wout rows 0..127   (issued SegF-top, used Seg7)
    float4 wbot[8];   // Wout rows 128..255 (issued Seg8-top, used Seg11)

    // ==== Seg 1: H partials — batch all 24 weight loads, then FMA ====
    {
      float2 w1[24];
#pragma unroll
      for (int w = 0; w < 24; ++w) {
        const int i = i0s + w;
        const float* Wp = (i < 128) ? (Wxh + i * DHH)
                        : (i < 256) ? (Whh + (i - 128) * DHH)
                                    : (Wrh + (i - 256) * DHH);
        w1[w] = *(const float2*)(Wp + j2s);
      }
      float2 acc = make_float2(0.f, 0.f);
#pragma unroll
      for (int k = 0; k < 6; ++k) {
        const float4 vv = *(const float4*)(V + i0s + 4 * k);
        const float vk[4] = { vv.x, vv.y, vv.z, vv.w };
#pragma unroll
        for (int u = 0; u < 4; ++u) {
          acc.x = fmaf(vk[u], w1[4 * k + u].x, acc.x);
          acc.y = fmaf(vk[u], w1[4 * k + u].y, acc.y);
        }
      }
      *(float2*)(U + s1 * 128 + j2s) = acc;
      bar_lds();
    }
    // ==== Seg 2: h = tanh(sum + bh) ====
    if (tid < DHH) {
      float a2 = bh[tid];
#pragma unroll
      for (int q2 = 0; q2 < 16; ++q2) a2 += U[q2 * 128 + tid];
      sH[tid] = tanh_(a2);
    }
    bar_lds();

    // ==== Seg 3: O partials — staged 16-load batches; halfslot interleaved ====
    {
      float2 wvA[16], wvB[16], w3h[16];
#pragma unroll
      for (int w = 0; w < 16; ++w) wvA[w] = p3base[w * stride3];
#pragma unroll
      for (int w = 0; w < 16; ++w) wvB[w] = p3base[(16 + w) * stride3];
      float2 acc = make_float2(0.f, 0.f);
#pragma unroll
      for (int k = 0; k < 4; ++k) {         // rows i03 .. i03+15 (wvA)
        const float4 hv = *(const float4*)(sH + i03 + 4 * k);
        const float hk[4] = { hv.x, hv.y, hv.z, hv.w };
#pragma unroll
        for (int u = 0; u < 4; ++u) {
          acc.x = fmaf(hk[u], wvA[4 * k + u].x, acc.x);
          acc.y = fmaf(hk[u], wvA[4 * k + u].y, acc.y);
        }
      }
      if (lane < 3) {                       // halfslot loads in flight over FMA-B
#pragma unroll
        for (int w = 0; w < 16; ++w)
          w3h[w] = *(const float2*)(Ww + (i0h + w) * 390 + cph2);
      }
#pragma unroll
      for (int k = 0; k < 4; ++k) {         // rows i03+16 .. i03+31 (wvB)
        const float4 hv = *(const float4*)(sH + i03 + 16 + 4 * k);
        const float hk[4] = { hv.x, hv.y, hv.z, hv.w };
#pragma unroll
        for (int u = 0; u < 4; ++u) {
          acc.x = fmaf(hk[u], wvB[4 * k + u].x, acc.x);
          acc.y = fmaf(hk[u], wvB[4 * k + u].y, acc.y);
        }
      }
      *(float2*)(U + tid * 2) = acc;
      if (lane < 3) {                       // 48 half-slots, 3 per wave
        float2 acch = make_float2(0.f, 0.f);
#pragma unroll
        for (int k = 0; k < 4; ++k) {
          const float4 hv = *(const float4*)(sH + i0h + 4 * k);
          const float hk[4] = { hv.x, hv.y, hv.z, hv.w };
#pragma unroll
          for (int u = 0; u < 4; ++u) {
            acch.x = fmaf(hk[u], w3h[4 * k + u].x, acch.x);
            acch.y = fmaf(hk[u], w3h[4 * k + u].y, acch.y);
          }
        }
        U[2096 + hs * 2]     = acch.x;
        U[2096 + hs * 2 + 1] = acch.y;
      }
      if (tid == 1023) {
        sP[0] = 0.f; sP[1] = 0.f; sP[2] = 0.f; sP[3] = 0.f; sP[4] = 0.f; sP[5] = 0.f;
      }
      bar_lds();
    }

    // ==== Seg F: fused combine+bias / knorm / e,a transforms / key packing /
    //      head scalars / sR zeroing / y-finalize(t-1); issues wtop prefetch ====
    {
      if (tid >= 512) {                     // Seg7's Wout rows, issued early
#pragma unroll
        for (int w = 0; w < 8; ++w)
          wtop[w] = *(const float4*)(Wout + (8 * slT + w) * DIN + j4T);
      }
      if (tid < 134) {                      // o_r col tid
        float v = 0.f;
#pragma unroll
        for (int q = 0; q < 4; ++q) v += U[tid + 524 * q];
        v += br[tid];
        sOr[tid] = v;
        if (tid < 128) {                    // waves 0,1 whole: |k_r|^2
          float s2 = waveSum(v * v);
          if (lane == 0) atomicAdd(&sP[0], s2);
        }
      } else if (tid == 134) {              // read-head scalars from U directly
        float sc[6];
#pragma unroll
        for (int j = 0; j < 6; ++j) {
          float v = 0.f;
#pragma unroll
          for (int q = 0; q < 4; ++q) v += U[(128 + j) + 524 * q];
          sc[j] = v + br[128 + j];
        }
        sP[80] = softplus_(sc[0]);
        sP[81] = sigmoid_(sc[1]);
        float mx = fmaxf(sc[2], fmaxf(sc[3], sc[4]));
        float e0 = __expf(sc[2] - mx), e1 = __expf(sc[3] - mx), e2 = __expf(sc[4] - mx);
        float es = e0 + e1 + e2;
        sP[82] = e0 / es; sP[83] = e1 / es; sP[84] = e2 / es;
        sP[85] = 1.0f + softplus_(sc[5]);
      } else if (tid == 135) {              // write-head scalars (o_w cols 128..133)
        float sc[6];
#pragma unroll
        for (int j = 0; j < 6; ++j) {
          float v = 0.f;
#pragma unroll
          for (int q = 0; q < 4; ++q) v += U[(262 + j) + 524 * q];
          sc[j] = v + bw[128 + j];
        }
        sP[86] = softplus_(sc[0]);
        sP[87] = sigmoid_(sc[1]);
        float mx = fmaxf(sc[2], fmaxf(sc[3], sc[4]));
        float e0 = __expf(sc[2] - mx), e1 = __expf(sc[3] - mx), e2 = __expf(sc[4] - mx);
        float es = e0 + e1 + e2;
        sP[88] = e0 / es; sP[89] = e1 / es; sP[90] = e2 / es;
        sP[91] = 1.0f + softplus_(sc[5]);
      } else if (tid >= 256 && tid < 512) { // e (256..383) / a (384..511)
        const int cc = tid + 12;            // combined col = 134 + cw, cw = tid-122
        float v = U[cc] + U[cc + 524] + U[cc + 1048];
        if (cc < 476) {
          v += U[cc + 1572];
        } else {                            // q=3 partial split into 2 halves
          const int cw = cc - 134;          // 342..389
          const int e = (cw >> 1) - 171;    // 0..23
          const int base = 2096 + 4 * e + (cw & 1);
          v += U[base] + U[base + 2];
        }
        v += bw[tid - 122];
        sOw[tid - 120] = (tid < 384) ? sigmoid_(v) : tanh_(v);
      } else if (tid >= 512 && tid < 640) { // k_w col cw (waves 8,9 whole): |k_w|^2
        const int cw = tid - 512;
        float v = 0.f;
#pragma unroll
        for (int q = 0; q < 4; ++q) v += U[(134 + cw) + 524 * q];
        v += bw[cw];
        sOw[cw] = v;
        float s2 = waveSum(v * v);
        if (lane == 0) atomicAdd(&sP[1], s2);
      } else if (tid >= 640 && tid < 768) {
        sR[tid - 640] = 0.f;                // Seg-9 ds_add target
      } else if (tid >= 768 && tid < 800) { // bf16 key packing from U (redundant combine)
        const int t2 = tid - 768;
        const int c = t2 & 15;
        union { uint4 v; unsigned short h[8]; } pk;
#pragma unroll
        for (int j = 0; j < 8; ++j) {
          const int col = c * 8 + j;        // 0..127
          float v = 0.f;
#pragma unroll
          for (int q = 0; q < 4; ++q)
            v += U[((t2 < 16) ? col : (134 + col)) + 524 * q];
          v += (t2 < 16) ? br[col] : bw[col];
          pk.h[j] = f2us(v);
        }
        if (t2 < 16) krP[c] = pk.v; else kwP[c] = pk.v;
      } else if (tid >= 896) {              // y-finalize(t-1) on idle waves 14,15
        if (t > 0) {
          const int c = tid - 896;
          float y = bout[c];
#pragma unroll
          for (int q = 0; q < 16; ++q) y += yP[q * 128 + c];
          out[((size_t)b * TSTEPS + (t - 1)) * DIN + c] = y;
        }
      }
      bar_lds();
    }

    // ==== Seg 6 (A): dots + norm + exp fused; bf16 keys; SR/SW via atomic ====
    {
      const float kn_r = sqrtf(sP[0]);
      const float kn_w = sqrtf(sP[1]);
      const float beta_r = sP[80], beta_w = sP[86];
      const int n = tid >> 1, hf = tid & 1;
      const int sw = (n >> 2) & 3;
      float dr = 0.f, dw = 0.f, ss = 0.f;
#pragma unroll
      for (int c = 0; c < 8; ++c) {
        const int cl = hf * 8 + c;
        const uint4 mv = memv[n * 16 + (cl ^ sw)];
        const uint4 kr = krP[cl];
        const uint4 kw = kwP[cl];
        const unsigned mw_[4] = { mv.x, mv.y, mv.z, mv.w };
        const unsigned krw[4] = { kr.x, kr.y, kr.z, kr.w };
        const unsigned kww[4] = { kw.x, kw.y, kw.z, kw.w };
#pragma unroll
        for (int j = 0; j < 4; ++j) {
          const float m0 = bf_lo(mw_[j]), m1 = bf_hi(mw_[j]);
          dr = fmaf(m0, bf_lo(krw[j]), dr); dr = fmaf(m1, bf_hi(krw[j]), dr);
          dw = fmaf(m0, bf_lo(kww[j]), dw); dw = fmaf(m1, bf_hi(kww[j]), dw);
          ss = fmaf(m0, m0, ss);            ss = fmaf(m1, m1, ss);
        }
      }
      dr += __shfl_xor(dr, 1);
      dw += __shfl_xor(dw, 1);
      ss += __shfl_xor(ss, 1);
      const float nr = sqrtf(ss);
      const float er = __expf(beta_r * dr / (nr * kn_r + EPSF));
      const float ew = __expf(beta_w * dw / (nr * kn_w + EPSF));
      if (hf == 0) { eR[n] = er; eW[n] = ew; }
      float s1_ = waveSum(er) * 0.5f;
      float s2_ = waveSum(ew) * 0.5f;
      if (lane == 0) { atomicAdd(&sP[2], s1_); atomicAdd(&sP[3], s2_); }
      bar_lds();
    }

    // ==== Seg 7: alpha (tid<512) + Y-top GEMV rows 0..127 (upper waves) ====
    {
      if (tid < NSLOT) {
        const float invE = 1.0f / sP[2];
        const float gr = sP[81], omg = 1.0f - sP[81];
        const int im = (tid - 1) & 511, ip = (tid + 1) & 511;
        const float wgm = gr * (eR[im] * invE) + omg * sWprev[im];
        const float wg0 = gr * (eR[tid] * invE) + omg * sWprev[tid];
        const float wgp = gr * (eR[ip] * invE) + omg * sWprev[ip];
        const float wt = sP[82] * wgp + sP[83] * wg0 + sP[84] * wgm;
        float p1 = (wt > 0.0f) ? __expf(sP[85] * __logf(wt)) : 0.0f;
        float P = waveSum(p1);
        sP1[tid] = p1;
        if (lane == 0) atomicAdd(&sP[4], P);
      } else {
        float4 acc = make_float4(0.f, 0.f, 0.f, 0.f);
        const float4 ha = *(const float4*)(sH + 8 * slT);
        const float4 hb = *(const float4*)(sH + 8 * slT + 4);
        const float hv[8] = { ha.x, ha.y, ha.z, ha.w, hb.x, hb.y, hb.z, hb.w };
#pragma unroll
        for (int w = 0; w < 8; ++w) {
          acc.x = fmaf(hv[w], wtop[w].x, acc.x); acc.y = fmaf(hv[w], wtop[w].y, acc.y);
          acc.z = fmaf(hv[w], wtop[w].z, acc.z); acc.w = fmaf(hv[w], wtop[w].w, acc.w);
        }
        *(float4*)(yP + slT * 128 + j4T) = acc;
      }
      bar_lds();
    }
    // ==== Seg 8: beta (tid<512, issues wbot prefetch) + x prefetch ====
    {
      if (tid < NSLOT) {
#pragma unroll
        for (int w = 0; w < 8; ++w)       // Seg11's Wout rows, issued early
          wbot[w] = *(const float4*)(Wout + (128 + 8 * slB + w) * DIN + j4B);
        const float pinv1 = 1.0f / (sP[4] + EPSF);
        const float invE = 1.0f / sP[3];
        const float gw = sP[87], omg = 1.0f - sP[87];
        const int im = (tid - 1) & 511, ip = (tid + 1) & 511;
        const float wgm = gw * (eW[im] * invE) + omg * (sP1[im] * pinv1);
        const float wg0 = gw * (eW[tid] * invE) + omg * (sP1[tid] * pinv1);
        const float wgp = gw * (eW[ip] * invE) + omg * (sP1[ip] * pinv1);
        sWr[tid] = sP1[tid] * pinv1;
        const float wt = sP[88] * wgp + sP[89] * wg0 + sP[90] * wgm;
        float p2 = (wt > 0.0f) ? __expf(sP[91] * __logf(wt)) : 0.0f;
        float P = waveSum(p2);
        U[tid] = p2;                       // raw p2 (eR region, dead)
        if (lane == 0) atomicAdd(&sP[5], P);
      } else if (tid < 512 + DIN && t + 1 < TSTEPS) {
        const int i = tid - 512;
        sXt[i] = x[((size_t)b * TSTEPS + (t + 1)) * DIN + i];
      }
      bar_lds();
    }

    // ==== Seg 9 (B): w_w inline; r-sweep + mem update; r via ds_add into sR ====
    {
      const float pinv2 = 1.0f / (sP[5] + EPSF);
      if (tid < NSLOT) sWprev[tid] = U[tid] * pinv2;   // next step's w_prev

      const int cl = l ^ ((g >> 2) & 3);
      float4 e4a = *(const float4*)(sOw + 136 + cl * 8);
      float4 e4b = *(const float4*)(sOw + 140 + cl * 8);
      float4 a4a = *(const float4*)(sOw + 264 + cl * 8);
      float4 a4b = *(const float4*)(sOw + 268 + cl * 8);
      const float e8[8] = { e4a.x, e4a.y, e4a.z, e4a.w, e4b.x, e4b.y, e4b.z, e4b.w };
      const float a8[8] = { a4a.x, a4a.y, a4a.z, a4a.w, a4b.x, a4b.y, a4b.z, a4b.w };
      float r8[8] = { 0, 0, 0, 0, 0, 0, 0, 0 };
#pragma unroll 2
      for (int it = 0; it < 8; ++it) {
        const int n = g + 64 * it;
        const float wrn = sWr[n];
        const float wwn = U[n] * pinv2;
        uint4 pk = memv[n * 16 + l];
        const unsigned wds[4] = { pk.x, pk.y, pk.z, pk.w };
        float m[8];
#pragma unroll
        for (int j = 0; j < 4; ++j) { m[2 * j] = bf_lo(wds[j]); m[2 * j + 1] = bf_hi(wds[j]); }
#pragma unroll
        for (int j = 0; j < 8; ++j) {
          r8[j] = fmaf(wrn, m[j], r8[j]);
          const float d = fmaf(-e8[j], m[j], a8[j]);
          m[j] = fmaf(wwn, d, m[j]);
        }
        pk.x = pkbf(m[0], m[1]);
        pk.y = pkbf(m[2], m[3]);
        pk.z = pkbf(m[4], m[5]);
        pk.w = pkbf(m[6], m[7]);
        memv[n * 16 + l] = pk;
      }
#pragma unroll
      for (int j = 0; j < 8; ++j) {          // partners g^1,g^2 share chunk
        r8[j] += __shfl_xor(r8[j], 16);
        r8[j] += __shfl_xor(r8[j], 32);
      }
      if (lane < 16) {                       // 16 waves x 8 ds_add into sR
#pragma unroll
        for (int j = 0; j < 8; ++j) atomicAdd(&sR[cl * 8 + j], r8[j]);
      }
      bar_lds();
    }

    // ==== Seg 11: Y-bottom GEMV rows 128..255 (tid<512), accumulate into yP ====
    {
      if (tid < 512) {
        float4 acc = *(const float4*)(yP + slB * 128 + j4B);
        const float4 ra = *(const float4*)(sR + 8 * slB);
        const float4 rb = *(const float4*)(sR + 8 * slB + 4);
        const float rv[8] = { ra.x, ra.y, ra.z, ra.w, rb.x, rb.y, rb.z, rb.w };
#pragma unroll
        for (int w = 0; w < 8; ++w) {
          acc.x = fmaf(rv[w], wbot[w].x, acc.x); acc.y = fmaf(rv[w], wbot[w].y, acc.y);
          acc.z = fmaf(rv[w], wbot[w].z, acc.z); acc.w = fmaf(rv[w], wbot[w].w, acc.w);
        }
        *(float4*)(yP + slB * 128 + j4B) = acc;
      }
      bar_lds();
    }
  }

  // final y
  if (tid < DIN) {
    float y = bout[tid];
#pragma unroll
    for (int q = 0; q < 16; ++q) y += yP[q * 128 + tid];
    out[((size_t)b * TSTEPS + (TSTEPS - 1)) * DIN + tid] = y;
  }
}

extern "C" void kernel_launch(void* const* d_in, const int* in_sizes, int n_in,
                              void* d_out, int out_size, void* d_ws, size_t ws_size,
                              hipStream_t stream) {
  (void)in_sizes; (void)n_in; (void)out_size; (void)d_ws; (void)ws_size;
  hipFuncSetAttribute(reinterpret_cast<const void*>(ntm_kernel),
                      hipFuncAttributeMaxDynamicSharedMemorySize, (int)LDS_BYTES);
  ntm_kernel<<<dim3(BSZ), dim3(NT), LDS_BYTES, stream>>>(
      (const float*)d_in[0], (const float*)d_in[1], (const float*)d_in[2],
      (const float*)d_in[3], (const float*)d_in[4], (const float*)d_in[5],
      (const float*)d_in[6], (const float*)d_in[7], (const float*)d_in[8],
      (const float*)d_in[9], (const float*)d_in[10],
      (float*)d_out);
}

// Round 4
// 852.600 us; speedup vs baseline: 2.4183x; 2.3867x over previous
//
#include <hip/hip_runtime.h>
#include <hip/hip_bf16.h>
#include <math.h>

#define NT 1024
#define BSZ 128
#define TSTEPS 32
#define DIN 128
#define DHH 128
#define NSLOT 512
#define EPSF 1e-8f

// LDS: [0,131072) mem bf16[512][128] XOR-swizzled; then float scratch F[7160]
static constexpr int F_FLOATS = 7160;
static constexpr size_t LDS_BYTES = 131072 + F_FLOATS * sizeof(float);

__device__ __forceinline__ float bf_lo(unsigned u) {
  union { unsigned u; float f; } c; c.u = u << 16; return c.f;
}
__device__ __forceinline__ float bf_hi(unsigned u) {
  union { unsigned u; float f; } c; c.u = u & 0xffff0000u; return c.f;
}
__device__ __forceinline__ unsigned short f2us(float f) {
  union { unsigned short s; __hip_bfloat16 h; } c; c.h = __float2bfloat16(f); return c.s;
}
__device__ __forceinline__ unsigned pkbf(float a, float b) {
  union { __hip_bfloat162 h2; unsigned u; } c;
  c.h2 = __float22bfloat162_rn(make_float2(a, b));
  return c.u;
}
__device__ __forceinline__ float sigmoid_(float x) { return 1.0f / (1.0f + __expf(-x)); }
__device__ __forceinline__ float softplus_(float x) {
  return fmaxf(x, 0.0f) + log1pf(__expf(-fabsf(x)));
}
__device__ __forceinline__ float tanh_(float x) {
  float e = __expf(-2.0f * fabsf(x));
  float t = (1.0f - e) / (1.0f + e);
  return copysignf(t, x);
}
__device__ __forceinline__ float waveSum(float v) {
#pragma unroll
  for (int m = 32; m >= 1; m >>= 1) v += __shfl_xor(v, m);
  return v;
}

// LDS-only barrier: waits LDS ops only, does NOT drain vmcnt, so the tail of
// each segment's in-flight global (weight) loads survives the barrier. All
// inter-thread traffic in this kernel is LDS (out is write-only), so
// lgkmcnt(0)+s_barrier gives full __syncthreads semantics here.
__device__ __forceinline__ void bar_lds() {
  asm volatile("s_waitcnt lgkmcnt(0)" ::: "memory");
  __builtin_amdgcn_s_barrier();
}

// One block (1024 threads) per batch element; all 32 steps in-block.
// mem in LDS, rows XOR-swizzled: stored uint4 slot u = c ^ ((n>>2)&3).
// HISTORY: R1-R3 all spilled (FETCH 1.8GB, WRITE 0.5GB, dur 2ms): this kernel
// compiles to a hard 64-VGPR budget (VGPR_Count=64 every round; waves_per_eu
// attribute had zero effect), so ANY cross-barrier register panel or batched
// load array >~64 live regs goes to scratch. R4 = exact R0 baseline structure
// (interleaved load-FMA, in-segment Wout loads, no hoisted panels) plus only
// the two register-neutral mechanisms:
//   A. bar_lds in-loop (no vmcnt drain at the 9 barriers/step).
//   B. V[384]=[x|h|r] contiguous; Seg1/Seg3 state reads as float4
//      (ds_read_b32 24->6 / 32->8 per thread-step), unroll 2 so weight-load
//      in-flight depth matches baseline's unroll-8 (~8 float2).
__global__ __launch_bounds__(NT, 4)
void ntm_kernel(const float* __restrict__ x,
                const float* __restrict__ Wxh,
                const float* __restrict__ Whh,
                const float* __restrict__ Wrh,
                const float* __restrict__ bh,
                const float* __restrict__ Wout,
                const float* __restrict__ bout,
                const float* __restrict__ Wr,
                const float* __restrict__ br,
                const float* __restrict__ Ww,
                const float* __restrict__ bw,
                float* __restrict__ out)
{
  extern __shared__ char smem[];
  uint4* memv = (uint4*)smem;              // bf16 mem, row n = 16 uint4 (swizzled)
  float* F = (float*)(smem + 131072);

  const int b = blockIdx.x;
  const int tid = threadIdx.x;
  const int g = tid >> 4, l = tid & 15;    // Phase-B mapping
  const int lane = tid & 63, wid = tid >> 6;

  float* U      = F + 0;      // 2560 multi-use: O/H partials (incl. [2096..2191]
                              //      half-slot partials); eR/eW; p2raw
  float* yP     = F + 2560;   // 2048 Y partials (live across step boundary)
  float* sWprev = F + 4608;   // 512
  float* sWr    = F + 5120;   // 512
  float* sP1    = F + 5632;   // 512 p1; aliased early by krP/kwP packed keys
  float* sOr    = F + 6144;   // 144 (134 used)
  float* sOw    = F + 6288;   // 392: [0..127] k_w, [136..263] e (16B-aligned), [264..391] a
  float* sXt    = F + 6680;   // 128  } contiguous V[384] = [x | h | r]
  float* sH     = F + 6808;   // 128  }  (order matters for Seg1 float4 reads)
  float* sR     = F + 6936;   // 128  }  (ds_add target in Seg 9)
  float* sP     = F + 7064;   // 96: [0]kr2 [1]kw2 [2]SR [3]SW [4]P1 [5]P2; [80..91] scalars
  float* V      = sXt;        // V[i]: i<128 x, i<256 h, else r
  uint4* krP    = (uint4*)(sP1 + 0);
  uint4* kwP    = (uint4*)(sP1 + 64);
  float* eR     = U + 0;
  float* eW     = U + 512;

  // ---- init ----
  {
    const unsigned short mb = f2us(1e-6f);
    const unsigned w32 = ((unsigned)mb << 16) | mb;
    const uint4 fv = make_uint4(w32, w32, w32, w32);
    for (int i = tid; i < NSLOT * DHH / 8; i += NT) memv[i] = fv;
  }
  for (int i = tid; i < NSLOT; i += NT) sWprev[i] = 1.0f / NSLOT;
  if (tid < DHH) { sH[tid] = 0.0f; sR[tid] = 0.0f; }
  if (tid < DIN) sXt[tid] = x[(size_t)b * TSTEPS * DIN + tid];
  __syncthreads();

  for (int t = 0; t < TSTEPS; ++t) {
    // ==== Seg 1: H partials (float2 weights interleaved; float4 V reads) ====
    {
      const int q = tid & 63, s = tid >> 6;   // s == wid: wave-uniform rows
      const int j2 = q * 2, i0 = s * 24;
      float2 acc = make_float2(0.f, 0.f);
#pragma unroll 2
      for (int k = 0; k < 6; ++k) {
        const float4 vv = *(const float4*)(V + i0 + 4 * k);
        const float vk[4] = { vv.x, vv.y, vv.z, vv.w };
#pragma unroll
        for (int u = 0; u < 4; ++u) {
          const int i = i0 + 4 * k + u;
          const float* Wp = (i < 128) ? (Wxh + i * DHH)
                          : (i < 256) ? (Whh + (i - 128) * DHH)
                                      : (Wrh + (i - 256) * DHH);
          const float2 wv = *(const float2*)(Wp + j2);
          acc.x = fmaf(vk[u], wv.x, acc.x);
          acc.y = fmaf(vk[u], wv.y, acc.y);
        }
      }
      *(float2*)(U + s * 128 + j2) = acc;
      bar_lds();
    }
    // ==== Seg 2: h = tanh(sum + bh) ====
    if (tid < DHH) {
      float a2 = bh[tid];
#pragma unroll
      for (int q2 = 0; q2 < 16; ++q2) a2 += U[q2 * 128 + tid];
      sH[tid] = tanh_(a2);
    }
    bar_lds();

    // ==== Seg 3: O partials — pass1 slot=tid (float4 sH reads); pass2 48
    //      half-slots, 3/wave (baseline form) ====
    {
      {
        const int s = tid;                  // 0..1023 (all valid, < 1048)
        const int q = (s >= 786) ? 3 : (s >= 524) ? 2 : (s >= 262) ? 1 : 0;
        const int P = s - 262 * q;
        const int i0 = 32 * q;
        const float2* p;
        int strideF2;
        if (P < 67) { p = (const float2*)(Wr + i0 * 134 + 2 * P); strideF2 = 67; }
        else        { p = (const float2*)(Ww + i0 * 390 + 2 * (P - 67)); strideF2 = 195; }
        float2 acc = make_float2(0.f, 0.f);
#pragma unroll 2
        for (int k = 0; k < 8; ++k) {
          const float4 hv = *(const float4*)(sH + i0 + 4 * k);
          const float hk[4] = { hv.x, hv.y, hv.z, hv.w };
#pragma unroll
          for (int u = 0; u < 4; ++u) {
            const float2 wv = p[(4 * k + u) * strideF2];
            acc.x = fmaf(hk[u], wv.x, acc.x);
            acc.y = fmaf(hk[u], wv.y, acc.y);
          }
        }
        *(float2*)(U + s * 2) = acc;
      }
      if (lane < 3) {                       // 48 half-slots: former slots 1024..1047
        const int hs = wid * 3 + lane;      // 0..47
        const int e = hs >> 1, hh = hs & 1;
        const int cp = 171 + e;             // Ww col-pair (P = 238+e >= 67)
        const int i0 = 96 + 16 * hh;
        const float2* p = (const float2*)(Ww + i0 * 390 + 2 * cp);
        float2 acc = make_float2(0.f, 0.f);
#pragma unroll 8
        for (int w = 0; w < 16; ++w) {
          const float v = sH[i0 + w];
          const float2 wv = *p;
          acc.x = fmaf(v, wv.x, acc.x);
          acc.y = fmaf(v, wv.y, acc.y);
          p += 195;
        }
        U[2096 + hs * 2]     = acc.x;
        U[2096 + hs * 2 + 1] = acc.y;
      }
      if (tid == 1023) {
        sP[0] = 0.f; sP[1] = 0.f; sP[2] = 0.f; sP[3] = 0.f; sP[4] = 0.f; sP[5] = 0.f;
      }
      bar_lds();
    }

    // ==== Seg F: fused combine+bias / knorm / e,a transforms / key packing /
    //      head scalars / sR zeroing / y-finalize(t-1) ====
    {
      if (tid < 134) {                      // o_r col tid
        float v = 0.f;
#pragma unroll
        for (int q = 0; q < 4; ++q) v += U[tid + 524 * q];
        v += br[tid];
        sOr[tid] = v;
        if (tid < 128) {                    // waves 0,1 whole: |k_r|^2
          float s2 = waveSum(v * v);
          if (lane == 0) atomicAdd(&sP[0], s2);
        }
      } else if (tid == 134) {              // read-head scalars from U directly
        float sc[6];
#pragma unroll
        for (int j = 0; j < 6; ++j) {
          float v = 0.f;
#pragma unroll
          for (int q = 0; q < 4; ++q) v += U[(128 + j) + 524 * q];
          sc[j] = v + br[128 + j];
        }
        sP[80] = softplus_(sc[0]);
        sP[81] = sigmoid_(sc[1]);
        float mx = fmaxf(sc[2], fmaxf(sc[3], sc[4]));
        float e0 = __expf(sc[2] - mx), e1 = __expf(sc[3] - mx), e2 = __expf(sc[4] - mx);
        float es = e0 + e1 + e2;
        sP[82] = e0 / es; sP[83] = e1 / es; sP[84] = e2 / es;
        sP[85] = 1.0f + softplus_(sc[5]);
      } else if (tid == 135) {              // write-head scalars (o_w cols 128..133)
        float sc[6];
#pragma unroll
        for (int j = 0; j < 6; ++j) {
          float v = 0.f;
#pragma unroll
          for (int q = 0; q < 4; ++q) v += U[(262 + j) + 524 * q];
          sc[j] = v + bw[128 + j];
        }
        sP[86] = softplus_(sc[0]);
        sP[87] = sigmoid_(sc[1]);
        float mx = fmaxf(sc[2], fmaxf(sc[3], sc[4]));
        float e0 = __expf(sc[2] - mx), e1 = __expf(sc[3] - mx), e2 = __expf(sc[4] - mx);
        float es = e0 + e1 + e2;
        sP[88] = e0 / es; sP[89] = e1 / es; sP[90] = e2 / es;
        sP[91] = 1.0f + softplus_(sc[5]);
      } else if (tid >= 256 && tid < 512) { // e (256..383) / a (384..511)
        const int cc = tid + 12;            // combined col = 134 + cw, cw = tid-122
        float v = U[cc] + U[cc + 524] + U[cc + 1048];
        if (cc < 476) {
          v += U[cc + 1572];
        } else {                            // q=3 partial split into 2 halves
          const int cw = cc - 134;          // 342..389
          const int e = (cw >> 1) - 171;    // 0..23
          const int base = 2096 + 4 * e + (cw & 1);
          v += U[base] + U[base + 2];
        }
        v += bw[tid - 122];
        sOw[tid - 120] = (tid < 384) ? sigmoid_(v) : tanh_(v);
      } else if (tid >= 512 && tid < 640) { // k_w col cw (waves 8,9 whole): |k_w|^2
        const int cw = tid - 512;
        float v = 0.f;
#pragma unroll
        for (int q = 0; q < 4; ++q) v += U[(134 + cw) + 524 * q];
        v += bw[cw];
        sOw[cw] = v;
        float s2 = waveSum(v * v);
        if (lane == 0) atomicAdd(&sP[1], s2);
      } else if (tid >= 640 && tid < 768) {
        sR[tid - 640] = 0.f;                // Seg-9 ds_add target
      } else if (tid >= 768 && tid < 800) { // bf16 key packing from U (redundant combine)
        const int t2 = tid - 768;
        const int c = t2 & 15;
        union { uint4 v; unsigned short h[8]; } pk;
#pragma unroll
        for (int j = 0; j < 8; ++j) {
          const int col = c * 8 + j;        // 0..127
          float v = 0.f;
#pragma unroll
          for (int q = 0; q < 4; ++q)
            v += U[((t2 < 16) ? col : (134 + col)) + 524 * q];
          v += (t2 < 16) ? br[col] : bw[col];
          pk.h[j] = f2us(v);
        }
        if (t2 < 16) krP[c] = pk.v; else kwP[c] = pk.v;
      } else if (tid >= 896) {              // y-finalize(t-1) on idle waves 14,15
        if (t > 0) {
          const int c = tid - 896;
          float y = bout[c];
#pragma unroll
          for (int q = 0; q < 16; ++q) y += yP[q * 128 + c];
          out[((size_t)b * TSTEPS + (t - 1)) * DIN + c] = y;
        }
      }
      bar_lds();
    }

    // ==== Seg 6 (A): dots + norm + exp fused; bf16 keys; SR/SW via atomic ====
    {
      const float kn_r = sqrtf(sP[0]);
      const float kn_w = sqrtf(sP[1]);
      const float beta_r = sP[80], beta_w = sP[86];
      const int n = tid >> 1, hf = tid & 1;
      const int sw = (n >> 2) & 3;
      float dr = 0.f, dw = 0.f, ss = 0.f;
#pragma unroll
      for (int c = 0; c < 8; ++c) {
        const int cl = hf * 8 + c;
        const uint4 mv = memv[n * 16 + (cl ^ sw)];
        const uint4 kr = krP[cl];
        const uint4 kw = kwP[cl];
        const unsigned mw_[4] = { mv.x, mv.y, mv.z, mv.w };
        const unsigned krw[4] = { kr.x, kr.y, kr.z, kr.w };
        const unsigned kww[4] = { kw.x, kw.y, kw.z, kw.w };
#pragma unroll
        for (int j = 0; j < 4; ++j) {
          const float m0 = bf_lo(mw_[j]), m1 = bf_hi(mw_[j]);
          dr = fmaf(m0, bf_lo(krw[j]), dr); dr = fmaf(m1, bf_hi(krw[j]), dr);
          dw = fmaf(m0, bf_lo(kww[j]), dw); dw = fmaf(m1, bf_hi(kww[j]), dw);
          ss = fmaf(m0, m0, ss);            ss = fmaf(m1, m1, ss);
        }
      }
      dr += __shfl_xor(dr, 1);
      dw += __shfl_xor(dw, 1);
      ss += __shfl_xor(ss, 1);
      const float nr = sqrtf(ss);
      const float er = __expf(beta_r * dr / (nr * kn_r + EPSF));
      const float ew = __expf(beta_w * dw / (nr * kn_w + EPSF));
      if (hf == 0) { eR[n] = er; eW[n] = ew; }
      float s1 = waveSum(er) * 0.5f;
      float s2 = waveSum(ew) * 0.5f;
      if (lane == 0) { atomicAdd(&sP[2], s1); atomicAdd(&sP[3], s2); }
      bar_lds();
    }

    // ==== Seg 7: alpha (tid<512) + Y-top GEMV rows 0..127 (upper waves) ====
    {
      if (tid < NSLOT) {
        const float invE = 1.0f / sP[2];
        const float gr = sP[81], omg = 1.0f - sP[81];
        const int im = (tid - 1) & 511, ip = (tid + 1) & 511;
        const float wgm = gr * (eR[im] * invE) + omg * sWprev[im];
        const float wg0 = gr * (eR[tid] * invE) + omg * sWprev[tid];
        const float wgp = gr * (eR[ip] * invE) + omg * sWprev[ip];
        const float wt = sP[82] * wgp + sP[83] * wg0 + sP[84] * wgm;
        float p1 = (wt > 0.0f) ? __expf(sP[85] * __logf(wt)) : 0.0f;
        float P = waveSum(p1);
        sP1[tid] = p1;
        if (lane == 0) atomicAdd(&sP[4], P);
      } else {
        const int p = tid - 512;
        const int j4 = (p & 31) * 4, sl = p >> 5;   // 16 segs x 8 rows (0..127)
        float4 acc = make_float4(0.f, 0.f, 0.f, 0.f);
#pragma unroll
        for (int w = 0; w < 8; ++w) {
          const float v = sH[8 * sl + w];
          const float4 wv = *(const float4*)(Wout + (8 * sl + w) * DIN + j4);
          acc.x = fmaf(v, wv.x, acc.x); acc.y = fmaf(v, wv.y, acc.y);
          acc.z = fmaf(v, wv.z, acc.z); acc.w = fmaf(v, wv.w, acc.w);
        }
        *(float4*)(yP + sl * 128 + j4) = acc;
      }
      bar_lds();
    }
    // ==== Seg 8: beta (tid<512) + x prefetch (idle upper waves) ====
    {
      if (tid < NSLOT) {
        const float pinv1 = 1.0f / (sP[4] + EPSF);
        const float invE = 1.0f / sP[3];
        const float gw = sP[87], omg = 1.0f - sP[87];
        const int im = (tid - 1) & 511, ip = (tid + 1) & 511;
        const float wgm = gw * (eW[im] * invE) + omg * (sP1[im] * pinv1);
        const float wg0 = gw * (eW[tid] * invE) + omg * (sP1[tid] * pinv1);
        const float wgp = gw * (eW[ip] * invE) + omg * (sP1[ip] * pinv1);
        sWr[tid] = sP1[tid] * pinv1;
        const float wt = sP[88] * wgp + sP[89] * wg0 + sP[90] * wgm;
        float p2 = (wt > 0.0f) ? __expf(sP[91] * __logf(wt)) : 0.0f;
        float P = waveSum(p2);
        U[tid] = p2;                       // raw p2 (eR region, dead)
        if (lane == 0) atomicAdd(&sP[5], P);
      } else if (tid < 512 + DIN && t + 1 < TSTEPS) {
        const int i = tid - 512;
        sXt[i] = x[((size_t)b * TSTEPS + (t + 1)) * DIN + i];
      }
      bar_lds();
    }

    // ==== Seg 9 (B): w_w inline; r-sweep + mem update; r via ds_add into sR ====
    {
      const float pinv2 = 1.0f / (sP[5] + EPSF);
      if (tid < NSLOT) sWprev[tid] = U[tid] * pinv2;   // next step's w_prev

      const int cl = l ^ ((g >> 2) & 3);
      float4 e4a = *(const float4*)(sOw + 136 + cl * 8);
      float4 e4b = *(const float4*)(sOw + 140 + cl * 8);
      float4 a4a = *(const float4*)(sOw + 264 + cl * 8);
      float4 a4b = *(const float4*)(sOw + 268 + cl * 8);
      const float e8[8] = { e4a.x, e4a.y, e4a.z, e4a.w, e4b.x, e4b.y, e4b.z, e4b.w };
      const float a8[8] = { a4a.x, a4a.y, a4a.z, a4a.w, a4b.x, a4b.y, a4b.z, a4b.w };
      float r8[8] = { 0, 0, 0, 0, 0, 0, 0, 0 };
#pragma unroll 2
      for (int it = 0; it < 8; ++it) {
        const int n = g + 64 * it;
        const float wrn = sWr[n];
        const float wwn = U[n] * pinv2;
        uint4 pk = memv[n * 16 + l];
        const unsigned wds[4] = { pk.x, pk.y, pk.z, pk.w };
        float m[8];
#pragma unroll
        for (int j = 0; j < 4; ++j) { m[2 * j] = bf_lo(wds[j]); m[2 * j + 1] = bf_hi(wds[j]); }
#pragma unroll
        for (int j = 0; j < 8; ++j) {
          r8[j] = fmaf(wrn, m[j], r8[j]);
          const float d = fmaf(-e8[j], m[j], a8[j]);
          m[j] = fmaf(wwn, d, m[j]);
        }
        pk.x = pkbf(m[0], m[1]);
        pk.y = pkbf(m[2], m[3]);
        pk.z = pkbf(m[4], m[5]);
        pk.w = pkbf(m[6], m[7]);
        memv[n * 16 + l] = pk;
      }
#pragma unroll
      for (int j = 0; j < 8; ++j) {          // partners g^1,g^2 share chunk
        r8[j] += __shfl_xor(r8[j], 16);
        r8[j] += __shfl_xor(r8[j], 32);
      }
      if (lane < 16) {                       // 16 waves x 8 ds_add into sR
#pragma unroll
        for (int j = 0; j < 8; ++j) atomicAdd(&sR[cl * 8 + j], r8[j]);
      }
      bar_lds();
    }

    // ==== Seg 11: Y-bottom GEMV rows 128..255 (tid<512), accumulate into yP ====
    {
      if (tid < 512) {
        const int j4 = (tid & 31) * 4, sl = tid >> 5;   // 16 segs x 8 rows
        float4 acc = *(const float4*)(yP + sl * 128 + j4);
#pragma unroll
        for (int w = 0; w < 8; ++w) {
          const float v = sR[8 * sl + w];
          const float4 wv = *(const float4*)(Wout + (128 + 8 * sl + w) * DIN + j4);
          acc.x = fmaf(v, wv.x, acc.x); acc.y = fmaf(v, wv.y, acc.y);
          acc.z = fmaf(v, wv.z, acc.z); acc.w = fmaf(v, wv.w, acc.w);
        }
        *(float4*)(yP + sl * 128 + j4) = acc;
      }
      bar_lds();
    }
  }

  // final y
  if (tid < DIN) {
    float y = bout[tid];
#pragma unroll
    for (int q = 0; q < 16; ++q) y += yP[q * 128 + tid];
    out[((size_t)b * TSTEPS + (TSTEPS - 1)) * DIN + tid] = y;
  }
}

extern "C" void kernel_launch(void* const* d_in, const int* in_sizes, int n_in,
                              void* d_out, int out_size, void* d_ws, size_t ws_size,
                              hipStream_t stream) {
  (void)in_sizes; (void)n_in; (void)out_size; (void)d_ws; (void)ws_size;
  hipFuncSetAttribute(reinterpret_cast<const void*>(ntm_kernel),
                      hipFuncAttributeMaxDynamicSharedMemorySize, (int)LDS_BYTES);
  ntm_kernel<<<dim3(BSZ), dim3(NT), LDS_BYTES, stream>>>(
      (const float*)d_in[0], (const float*)d_in[1], (const float*)d_in[2],
      (const float*)d_in[3], (const float*)d_in[4], (const float*)d_in[5],
      (const float*)d_in[6], (const float*)d_in[7], (const float*)d_in[8],
      (const float*)d_in[9], (const float*)d_in[10],
      (float*)d_out);
}